// Round 13
// baseline (704.360 us; speedup 1.0000x reference)
//
#include <hip/hip_runtime.h>

// EncoderBlock: B=8, S=2048, D=1024, H=4096, single-head attn (scale AFTER softmax),
// LN -> QKV -> scores -> softmax*(1/32) -> PV -> MLP(Swish) -> +residual.
// Round 13: R12 base (594us) + ONE change: 32x32x16 MFMA (bf16/f16) in the GEMM core.
// Same FLOPs on the faster 32x32 pipe (2382 vs 2075 TF ubench), half the MFMA issue
// slots. Wave tile 64x64 = 2x2 blocks of 32x32, acc 4x f32x16. LDS layout/swizzle/
// staging/band-raster identical to R12 (reads become 4-way bank-aliased; modeled
// LDS 202cyc/iter < pipe 258cyc -> acceptable). WS = 190,840,832 B, overlay = R6/R8.

#define Bb_ 8
#define Ss_ 2048
#define Dd_ 1024
#define Hh_ 4096

typedef __bf16 bf16;
typedef _Float16 f16;
typedef __attribute__((ext_vector_type(8))) __bf16 bf16x8;
typedef __attribute__((ext_vector_type(8))) _Float16 f16x8;
typedef __attribute__((ext_vector_type(4))) __bf16 bf16x4;
typedef __attribute__((ext_vector_type(4))) float f32x4;
typedef __attribute__((ext_vector_type(16))) float f32x16;

enum { EPI_QKV = 0, EPI_F16 = 1, EPI_AOS = 2, EPI_SWISH = 3, EPI_RESID = 4 };

__device__ __forceinline__ void gload16(const bf16* g, bf16* l) {
  __builtin_amdgcn_global_load_lds(
      (const __attribute__((address_space(1))) void*)g,
      (__attribute__((address_space(3))) void*)l, 16, 0, 0);
}

#define SETP(x) __builtin_amdgcn_s_setprio(x)

// ---------- transpose-cast: W[K][N] f32 -> WT[N][K] bf16 ----------
__global__ __launch_bounds__(256) void tcast_k(const float* __restrict__ W,
                                               bf16* __restrict__ WT, int K, int N) {
  __shared__ float tile[32][33];
  const int tn0 = blockIdx.x * 32;
  const int tk0 = blockIdx.y * 32;
  const int t = threadIdx.x;
  const int c = t & 31;
  const int r4 = t >> 5;
#pragma unroll
  for (int i = 0; i < 4; i++) {
    int r = r4 + i * 8;
    tile[r][c] = W[(long)(tk0 + r) * N + (tn0 + c)];
  }
  __syncthreads();
#pragma unroll
  for (int i = 0; i < 4; i++) {
    int r = r4 + i * 8;
    WT[(long)(tn0 + r) * K + (tk0 + c)] = (bf16)tile[c][r];
  }
}

// ---------- fp16 transpose: v[z][2048][1024] -> vT[z][1024][2048] ----------
__global__ __launch_bounds__(256) void tbf16_k(const f16* __restrict__ V,
                                               f16* __restrict__ VT) {
  __shared__ f16 tile[64][72];
  const long z = blockIdx.z;
  const int n0 = blockIdx.x * 64;
  const int k0 = blockIdx.y * 64;
  const int t = threadIdx.x;
  const int r = t >> 3;
  const int c = (t & 7) * 8;
  const f16* Vb = V + z * (long)(Ss_ * Dd_);
  f16* VTb = VT + z * (long)(Dd_ * Ss_);
#pragma unroll
  for (int i = 0; i < 2; i++)
    *(f16x8*)&tile[r + i * 32][c] =
        *(const f16x8*)(Vb + (long)(k0 + r + i * 32) * Dd_ + n0 + c);
  __syncthreads();
#pragma unroll
  for (int i = 0; i < 2; i++) {
    const int n = r + i * 32;
    f16x8 ov;
#pragma unroll
    for (int j = 0; j < 8; j++) ov[j] = tile[c + j][n];
    *(f16x8*)(VTb + (long)(n0 + n) * Ss_ + k0 + c) = ov;
  }
}

// ---------- LayerNorm: x[row][1024] f32 -> xn bf16 ----------
__global__ __launch_bounds__(256) void ln_k(const float* __restrict__ x,
                                            const float* __restrict__ gamma,
                                            const float* __restrict__ beta,
                                            bf16* __restrict__ xn) {
  const long row = blockIdx.x;
  const float* xr = x + row * Dd_;
  const int t = threadIdx.x;
  float4 v = *(const float4*)(xr + t * 4);
  float s = v.x + v.y + v.z + v.w;
  float sq = v.x * v.x + v.y * v.y + v.z * v.z + v.w * v.w;
#pragma unroll
  for (int o = 32; o > 0; o >>= 1) {
    s += __shfl_down(s, o);
    sq += __shfl_down(sq, o);
  }
  __shared__ float ls[4], lq[4];
  const int wid = t >> 6;
  if ((t & 63) == 0) { ls[wid] = s; lq[wid] = sq; }
  __syncthreads();
  if (t == 0) {
    float S = ls[0] + ls[1] + ls[2] + ls[3];
    float Q = lq[0] + lq[1] + lq[2] + lq[3];
    float mu = S * (1.0f / Dd_);
    float var = Q * (1.0f / Dd_) - mu * mu;
    ls[0] = mu;
    lq[0] = rsqrtf(var + 1e-5f);
  }
  __syncthreads();
  const float mu = ls[0], rstd = lq[0];
  float4 g = *(const float4*)(gamma + t * 4);
  float4 be = *(const float4*)(beta + t * 4);
  bf16x4 ov;
  ov[0] = (bf16)((v.x - mu) * rstd * g.x + be.x);
  ov[1] = (bf16)((v.y - mu) * rstd * g.y + be.y);
  ov[2] = (bf16)((v.z - mu) * rstd * g.z + be.z);
  ov[3] = (bf16)((v.w - mu) * rstd * g.w + be.w);
  *(bf16x4*)(xn + row * Dd_ + t * 4) = ov;
}

// ---------- softmax: fp16 scores (two slabs) -> fp16 probs (UNSCALED), in place ----------
__global__ __launch_bounds__(256) void softmax16_k(f16* __restrict__ lo,
                                                   f16* __restrict__ hi) {
  const long row = blockIdx.x;
  const long z = row >> 11;
  f16* sr = (z < 4 ? lo + z * 4194304L : hi + (z - 4) * 4194304L) +
            (row & 2047) * (long)Ss_;
  const int t = threadIdx.x;
  f16x8 v = *(const f16x8*)(sr + t * 8);
  float f[8];
#pragma unroll
  for (int j = 0; j < 8; j++) f[j] = (float)v[j];
  float vm = f[0];
#pragma unroll
  for (int j = 1; j < 8; j++) vm = fmaxf(vm, f[j]);
  __shared__ float red[4];
#pragma unroll
  for (int o = 32; o > 0; o >>= 1) vm = fmaxf(vm, __shfl_xor(vm, o));
  const int wid = t >> 6;
  if ((t & 63) == 0) red[wid] = vm;
  __syncthreads();
  vm = fmaxf(fmaxf(red[0], red[1]), fmaxf(red[2], red[3]));
  float e[8], s = 0.f;
#pragma unroll
  for (int j = 0; j < 8; j++) { e[j] = __expf(f[j] - vm); s += e[j]; }
#pragma unroll
  for (int o = 32; o > 0; o >>= 1) s += __shfl_xor(s, o);
  __syncthreads();
  if ((t & 63) == 0) red[wid] = s;
  __syncthreads();
  s = red[0] + red[1] + red[2] + red[3];
  const float rs = 1.0f / s;  // 1/32 applied in PV epilogue
  f16x8 ov;
#pragma unroll
  for (int j = 0; j < 8; j++) ov[j] = (f16)(e[j] * rs);
  *(f16x8*)(sr + t * 8) = ov;
}

// ========== 128x128xK GEMM, BK=64, dbuf 64KiB LDS, 4 waves, 2 blocks/CU ==========
// C = A[M][K] * B[N][K]^T. DT=0 bf16 MFMA, DT=1 f16 MFMA. 32x32x16 MFMA core:
// wave tile 64x64 = 2x2 blocks of 32x32; per K-64: 16 reads, 16 MFMA (4 kk x 2mb x 2nb).
// Input frag: row = lane&31, k = kk*16 + 8*(lane>>5) + j (b128 per read).
// C/D frag [m74/m101]: col = lane&31, row = (reg&3) + 8*(reg>>2) + 4*(lane>>5).
// LDS: L[buf2][op2][128*64] swizzled: (r,k) at elem r*64 + (k ^ ((r&7)*8));
// staged via pre-swizzled GLOBAL source + linear gload_lds dest (rule 21).
// Loop: STAGE(t+1) -> plain-C++ READS(t) -> MFMA (compiler-interleaved) -> syncthreads.
// XCD-chunked L2 band raster (R12): bands of H m-rows sweep all n per XCD chunk.
template <int EPI, int DT>
__global__ __launch_bounds__(256, 2) void gemmdb_k(
    const bf16* __restrict__ Ab, const bf16* __restrict__ Bbp, void* __restrict__ Cb,
    const float* __restrict__ bias, const float* __restrict__ resid,
    int K, int lda, int ldb, int ldc, long astr, long bstr, long cstr) {
  extern __shared__ bf16 L[];  // 2*2*8192 elems = 64 KiB
  const int t = threadIdx.x;
  const int lane = t & 63;
  const int w = t >> 6;             // 0..3
  const int wm = w >> 1, wn = w & 1;

  // ---- XCD-chunked band raster (bijective; all grids: nwg%8==0, gx|cpx, H|R) ----
  const int gx = gridDim.x;                 // n tiles
  const int nwg = gx * gridDim.y;
  const int dd = blockIdx.y * gx + blockIdx.x;
  const int cpx = nwg >> 3;                 // tiles per XCD chunk
  const int xcd = dd & 7;                   // dispatch round-robins XCDs
  const int idx = dd >> 3;                  // 0..cpx-1 within chunk
  const int R = cpx / gx;                   // m-rows per chunk
  const int H = (R >= 8) ? 8 : R;           // band height (H | R for all our grids)
  const int bandsz = H * gx;
  const int bnd = idx / bandsz;
  const int rr = idx % bandsz;
  const int m_t = xcd * R + bnd * H + (rr % H);
  const int n_t = rr / H;
  const int m0 = m_t * 128;
  const int n0 = n_t * 128;

  const long z = blockIdx.z;
  const bf16* A;
  if constexpr (EPI == EPI_AOS) {
    A = (z < 4 ? Ab + z * astr : (const bf16*)bias + (z - 4) * astr);
  } else if constexpr (EPI == EPI_RESID) {
    const long qo[4] = {0, 33554432, 50331648, 67108864};  // h quarters (elem offs)
    A = Ab + qo[m0 >> 12] - (long)(m0 & ~4095) * lda;
  } else {
    A = Ab + z * astr;
  }
  const bf16* Bp = Bbp + z * bstr;

  // staging: 128 rows -> 16 chunks of 8 rows (1KB each); wave w stages A,B chunks 4w..4w+3.
  // lane l -> row chunk*8 + (l>>3); pre-swizzled source col = 8*((l&7)^(l>>3)).
  const int lrow = lane >> 3;
  const int sc = 8 * ((lane & 7) ^ lrow);
  const bf16* gA[4];
  const bf16* gB[4];
#pragma unroll
  for (int j = 0; j < 4; ++j) {
    const int r = (w * 4 + j) * 8 + lrow;
    gA[j] = A + (long)(m0 + r) * lda + sc;
    gB[j] = Bp + (long)(n0 + r) * ldb + sc;
  }

#define STAGE(buf, tau)                                                          \
  do {                                                                           \
    _Pragma("unroll") for (int j_ = 0; j_ < 4; ++j_)                             \
        gload16(gA[j_] + (long)(tau) * 64,                                       \
                &L[((buf)*2 + 0) * 8192 + (w * 4 + j_) * 512]);                  \
    _Pragma("unroll") for (int j_ = 0; j_ < 4; ++j_)                             \
        gload16(gB[j_] + (long)(tau) * 64,                                       \
                &L[((buf)*2 + 1) * 8192 + (w * 4 + j_) * 512]);                  \
  } while (0)

  // fragment reads (32x32x16): A rows wm*64 + mb*32 + r32, B rows wn*64 + nb*32 + r32;
  // k = kk*16 + kh (kh = 8*(lane>>5)); 16 plain b128 reads per K-64 tile.
  const int r32 = lane & 31;
  const int kh = (lane >> 5) * 8;
  const int xorv = (r32 & 7) * 8;

#define READ_ALL(ab, bb)                                                         \
  _Pragma("unroll") for (int mb_ = 0; mb_ < 2; ++mb_)                            \
  _Pragma("unroll") for (int kk_ = 0; kk_ < 4; ++kk_) {                          \
    a[mb_][kk_] = *(const bf16x8*)&L[(ab) + (wm * 64 + mb_ * 32 + r32) * 64 +    \
                                     ((kk_ * 16 + kh) ^ xorv)];                  \
    b[mb_][kk_] = *(const bf16x8*)&L[(bb) + (wn * 64 + mb_ * 32 + r32) * 64 +    \
                                     ((kk_ * 16 + kh) ^ xorv)];                  \
  }
#define MM(av, bv, cv)                                                           \
  (DT ? __builtin_amdgcn_mfma_f32_32x32x16_f16(                                  \
            __builtin_bit_cast(f16x8, av), __builtin_bit_cast(f16x8, bv), cv,    \
            0, 0, 0)                                                             \
      : __builtin_amdgcn_mfma_f32_32x32x16_bf16(av, bv, cv, 0, 0, 0))

  f32x16 acc[2][2] = {};
  bf16x8 a[2][4], b[2][4];

  // prologue: stage tile 0 into buf0
  STAGE(0, 0);
  __syncthreads();

  const int NT = K >> 6;
  for (int tt = 0; tt < NT; ++tt) {
    const int cur = tt & 1;
    const int ab = (cur * 2 + 0) * 8192;
    const int bb = (cur * 2 + 1) * 8192;
    const bool nf = (tt + 1 < NT);
    if (nf) STAGE(cur ^ 1, tt + 1);
    READ_ALL(ab, bb);
    SETP(1);
#pragma unroll
    for (int kk = 0; kk < 4; ++kk)
#pragma unroll
      for (int mb = 0; mb < 2; ++mb)
#pragma unroll
        for (int nb = 0; nb < 2; ++nb)
          acc[mb][nb] = MM(a[mb][kk], b[nb][kk], acc[mb][nb]);
    SETP(0);
    __syncthreads();  // vmcnt(0)+lgkmcnt(0)+barrier: stage(t+1) visible, reads drained
  }

  // epilogue (32x32 C/D): col = lane&31, row = (reg&3) + 8*(reg>>2) + 4*(lane>>5)
  const int row0 = m0 + wm * 64;
  const int col0 = n0 + wn * 64;
  const int rbase = (lane >> 5) * 4;
#pragma unroll
  for (int mb = 0; mb < 2; mb++) {
#pragma unroll
    for (int nb = 0; nb < 2; nb++) {
#pragma unroll
      for (int reg = 0; reg < 16; reg++) {
        const long gm = row0 + mb * 32 + (reg & 3) + 8 * (reg >> 2) + rbase;
        const int gn = col0 + nb * 32 + r32;
        float val = acc[mb][nb][reg];
        if constexpr (EPI == EPI_QKV) {
          if (z < 2) {
            ((bf16*)Cb)[z * cstr + gm * ldc + gn] = (bf16)val;   // q,k bf16
          } else {
            ((f16*)resid)[gm * (long)ldc + gn] = (f16)val;       // v rows fp16
          }
        } else if constexpr (EPI == EPI_F16) {
          ((f16*)Cb)[z * cstr + gm * ldc + gn] = (f16)val;
        } else if constexpr (EPI == EPI_AOS) {
          ((bf16*)Cb)[z * cstr + gm * ldc + gn] = (bf16)(val * 0.03125f);
        } else if constexpr (EPI == EPI_SWISH) {
          const long qoc[4] = {0, 33554432, 50331648, 67108864};
          bf16* hq = (bf16*)Cb + qoc[m0 >> 12];
          float hv = val + bias[gn];
          hq[(long)(gm & 4095) * ldc + gn] = (bf16)(hv / (1.0f + __expf(-hv)));
        } else {  // EPI_RESID
          ((float*)Cb)[gm * (long)ldc + gn] = val + bias[gn] + resid[gm * (long)ldc + gn];
        }
      }
    }
  }
#undef STAGE
#undef READ_ALL
#undef MM
}

extern "C" void kernel_launch(void* const* d_in, const int* in_sizes, int n_in,
                              void* d_out, int out_size, void* d_ws, size_t ws_size,
                              hipStream_t stream) {
  const float* x  = (const float*)d_in[0];
  const float* g  = (const float*)d_in[1];
  const float* be = (const float*)d_in[2];
  const float* Wq = (const float*)d_in[3];
  const float* Wk = (const float*)d_in[4];
  const float* Wv = (const float*)d_in[5];
  const float* W1 = (const float*)d_in[6];
  const float* b1 = (const float*)d_in[7];
  const float* W2 = (const float*)d_in[8];
  const float* b2 = (const float*)d_in[9];

  hipFuncSetAttribute((const void*)&gemmdb_k<EPI_QKV, 0>,
                      hipFuncAttributeMaxDynamicSharedMemorySize, 65536);
  hipFuncSetAttribute((const void*)&gemmdb_k<EPI_F16, 0>,
                      hipFuncAttributeMaxDynamicSharedMemorySize, 65536);
  hipFuncSetAttribute((const void*)&gemmdb_k<EPI_AOS, 1>,
                      hipFuncAttributeMaxDynamicSharedMemorySize, 65536);
  hipFuncSetAttribute((const void*)&gemmdb_k<EPI_SWISH, 0>,
                      hipFuncAttributeMaxDynamicSharedMemorySize, 65536);
  hipFuncSetAttribute((const void*)&gemmdb_k<EPI_RESID, 0>,
                      hipFuncAttributeMaxDynamicSharedMemorySize, 65536);

  // ---- workspace overlay (bytes); identical to R6/R8/R11/R12 ----
  char* ws = (char*)d_ws;
  bf16* xn        = (bf16*)(ws + 0);
  f16*  scores_lo = (f16*)(ws + 0);            // z=0..3 after xn dies
  bf16* q         = (bf16*)(ws + 33554432);
  bf16* ao        = (bf16*)(ws + 33554432);    // after q dies
  bf16* kk        = (bf16*)(ws + 67108864);
  f16*  vT        = (f16*)(ws + 100663296);
  f16*  vrows     = (f16*)(ws + 134217728);
  f16*  scores_hi = (f16*)(ws + 134217728);    // z=4..7 after vrows dies
  bf16* wqT       = (bf16*)(ws + 167772160);
  bf16* w1T       = (bf16*)(ws + 174063616);
  bf16* w2T       = (bf16*)(ws + 182452224);
  // h quarters at byte offsets {0, 67108864, 100663296, 134217728} (EPI_SWISH/RESID).

  tcast_k<<<dim3(32, 32), 256, 0, stream>>>(Wq, wqT, 1024, 1024);
  tcast_k<<<dim3(32, 32), 256, 0, stream>>>(Wk, wqT + 1048576, 1024, 1024);
  tcast_k<<<dim3(32, 32), 256, 0, stream>>>(Wv, wqT + 2097152, 1024, 1024);
  tcast_k<<<dim3(128, 32), 256, 0, stream>>>(W1, w1T, 1024, 4096);
  tcast_k<<<dim3(32, 128), 256, 0, stream>>>(W2, w2T, 4096, 1024);

  ln_k<<<16384, 256, 0, stream>>>(x, g, be, xn);

  // QKV: z=0,1 -> q,k bf16; z=2 -> v rows fp16 via resid ptr
  gemmdb_k<EPI_QKV, 0><<<dim3(8, 128, 3), 256, 65536, stream>>>(
      xn, wqT, q, nullptr, (const float*)vrows, 1024, 1024, 1024, 1024,
      0L, 1048576L, 16777216L);

  tbf16_k<<<dim3(16, 32, 8), 256, 0, stream>>>(vrows, vT);

  // scores: two fp16 slabs
  gemmdb_k<EPI_F16, 0><<<dim3(16, 16, 4), 256, 65536, stream>>>(
      q, kk, scores_lo, nullptr, nullptr,
      1024, 1024, 1024, 2048, 2097152L, 2097152L, 4194304L);
  gemmdb_k<EPI_F16, 0><<<dim3(16, 16, 4), 256, 65536, stream>>>(
      q + 4L * 2097152, kk + 4L * 2097152, scores_hi, nullptr, nullptr,
      1024, 1024, 1024, 2048, 2097152L, 2097152L, 4194304L);

  softmax16_k<<<16384, 256, 0, stream>>>(scores_lo, scores_hi);

  // PV: single launch over all 8 batches; A slab-split inside kernel (f16 MFMA)
  gemmdb_k<EPI_AOS, 1><<<dim3(8, 16, 8), 256, 65536, stream>>>(
      (const bf16*)scores_lo, (const bf16*)vT, ao, (const float*)scores_hi, nullptr,
      2048, 2048, 2048, 1024, 4194304L, 2097152L, 2097152L);

  // MLP1: h (quartered) = swish(ao @ W1 + b1)
  gemmdb_k<EPI_SWISH, 0><<<dim3(32, 128, 1), 256, 65536, stream>>>(
      ao, w1T, ws, b1, nullptr, 1024, 1024, 1024, 4096, 0L, 0L, 0L);
  // MLP2: out = h @ W2 + b2 + x (A from h quarters)
  gemmdb_k<EPI_RESID, 0><<<dim3(8, 128, 1), 256, 65536, stream>>>(
      (const bf16*)ws, w2T, d_out, b2, x, 4096, 4096, 4096, 1024, 0L, 0L, 0L);
}

// Round 14
// 697.099 us; speedup vs baseline: 1.0104x; 1.0104x over previous
//
#include <hip/hip_runtime.h>

// EncoderBlock: B=8, S=2048, D=1024, H=4096, single-head attn (scale AFTER softmax),
// LN -> QKV -> scores -> softmax*(1/32) -> PV -> MLP(Swish) -> +residual.
// Round 14: R12 core reverted (16x16x32 MFMA, 594us best) + ONE change: BK=32 ->
// 32KiB dbuf LDS -> 4 blocks/CU (launch_bounds(256,4)). R8 proved block-overlap is
// the stall-filler (1->2 blocks = +15%); R10's 3-block failure was L2 thrash, since
// fixed by R12's band raster. Swizzle = R9-verified BK=32 scheme (0 conflicts).
// WS = 190,840,832 B, overlay identical to R6/R8/R11/R12.

#define Bb_ 8
#define Ss_ 2048
#define Dd_ 1024
#define Hh_ 4096

typedef __bf16 bf16;
typedef _Float16 f16;
typedef __attribute__((ext_vector_type(8))) __bf16 bf16x8;
typedef __attribute__((ext_vector_type(8))) _Float16 f16x8;
typedef __attribute__((ext_vector_type(4))) __bf16 bf16x4;
typedef __attribute__((ext_vector_type(4))) float f32x4;

enum { EPI_QKV = 0, EPI_F16 = 1, EPI_AOS = 2, EPI_SWISH = 3, EPI_RESID = 4 };

__device__ __forceinline__ void gload16(const bf16* g, bf16* l) {
  __builtin_amdgcn_global_load_lds(
      (const __attribute__((address_space(1))) void*)g,
      (__attribute__((address_space(3))) void*)l, 16, 0, 0);
}

#define SETP(x) __builtin_amdgcn_s_setprio(x)

// ---------- transpose-cast: W[K][N] f32 -> WT[N][K] bf16 ----------
__global__ __launch_bounds__(256) void tcast_k(const float* __restrict__ W,
                                               bf16* __restrict__ WT, int K, int N) {
  __shared__ float tile[32][33];
  const int tn0 = blockIdx.x * 32;
  const int tk0 = blockIdx.y * 32;
  const int t = threadIdx.x;
  const int c = t & 31;
  const int r4 = t >> 5;
#pragma unroll
  for (int i = 0; i < 4; i++) {
    int r = r4 + i * 8;
    tile[r][c] = W[(long)(tk0 + r) * N + (tn0 + c)];
  }
  __syncthreads();
#pragma unroll
  for (int i = 0; i < 4; i++) {
    int r = r4 + i * 8;
    WT[(long)(tn0 + r) * K + (tk0 + c)] = (bf16)tile[c][r];
  }
}

// ---------- fp16 transpose: v[z][2048][1024] -> vT[z][1024][2048] ----------
__global__ __launch_bounds__(256) void tbf16_k(const f16* __restrict__ V,
                                               f16* __restrict__ VT) {
  __shared__ f16 tile[64][72];
  const long z = blockIdx.z;
  const int n0 = blockIdx.x * 64;
  const int k0 = blockIdx.y * 64;
  const int t = threadIdx.x;
  const int r = t >> 3;
  const int c = (t & 7) * 8;
  const f16* Vb = V + z * (long)(Ss_ * Dd_);
  f16* VTb = VT + z * (long)(Dd_ * Ss_);
#pragma unroll
  for (int i = 0; i < 2; i++)
    *(f16x8*)&tile[r + i * 32][c] =
        *(const f16x8*)(Vb + (long)(k0 + r + i * 32) * Dd_ + n0 + c);
  __syncthreads();
#pragma unroll
  for (int i = 0; i < 2; i++) {
    const int n = r + i * 32;
    f16x8 ov;
#pragma unroll
    for (int j = 0; j < 8; j++) ov[j] = tile[c + j][n];
    *(f16x8*)(VTb + (long)(n0 + n) * Ss_ + k0 + c) = ov;
  }
}

// ---------- LayerNorm: x[row][1024] f32 -> xn bf16 ----------
__global__ __launch_bounds__(256) void ln_k(const float* __restrict__ x,
                                            const float* __restrict__ gamma,
                                            const float* __restrict__ beta,
                                            bf16* __restrict__ xn) {
  const long row = blockIdx.x;
  const float* xr = x + row * Dd_;
  const int t = threadIdx.x;
  float4 v = *(const float4*)(xr + t * 4);
  float s = v.x + v.y + v.z + v.w;
  float sq = v.x * v.x + v.y * v.y + v.z * v.z + v.w * v.w;
#pragma unroll
  for (int o = 32; o > 0; o >>= 1) {
    s += __shfl_down(s, o);
    sq += __shfl_down(sq, o);
  }
  __shared__ float ls[4], lq[4];
  const int wid = t >> 6;
  if ((t & 63) == 0) { ls[wid] = s; lq[wid] = sq; }
  __syncthreads();
  if (t == 0) {
    float S = ls[0] + ls[1] + ls[2] + ls[3];
    float Q = lq[0] + lq[1] + lq[2] + lq[3];
    float mu = S * (1.0f / Dd_);
    float var = Q * (1.0f / Dd_) - mu * mu;
    ls[0] = mu;
    lq[0] = rsqrtf(var + 1e-5f);
  }
  __syncthreads();
  const float mu = ls[0], rstd = lq[0];
  float4 g = *(const float4*)(gamma + t * 4);
  float4 be = *(const float4*)(beta + t * 4);
  bf16x4 ov;
  ov[0] = (bf16)((v.x - mu) * rstd * g.x + be.x);
  ov[1] = (bf16)((v.y - mu) * rstd * g.y + be.y);
  ov[2] = (bf16)((v.z - mu) * rstd * g.z + be.z);
  ov[3] = (bf16)((v.w - mu) * rstd * g.w + be.w);
  *(bf16x4*)(xn + row * Dd_ + t * 4) = ov;
}

// ---------- softmax: fp16 scores (two slabs) -> fp16 probs (UNSCALED), in place ----------
__global__ __launch_bounds__(256) void softmax16_k(f16* __restrict__ lo,
                                                   f16* __restrict__ hi) {
  const long row = blockIdx.x;
  const long z = row >> 11;
  f16* sr = (z < 4 ? lo + z * 4194304L : hi + (z - 4) * 4194304L) +
            (row & 2047) * (long)Ss_;
  const int t = threadIdx.x;
  f16x8 v = *(const f16x8*)(sr + t * 8);
  float f[8];
#pragma unroll
  for (int j = 0; j < 8; j++) f[j] = (float)v[j];
  float vm = f[0];
#pragma unroll
  for (int j = 1; j < 8; j++) vm = fmaxf(vm, f[j]);
  __shared__ float red[4];
#pragma unroll
  for (int o = 32; o > 0; o >>= 1) vm = fmaxf(vm, __shfl_xor(vm, o));
  const int wid = t >> 6;
  if ((t & 63) == 0) red[wid] = vm;
  __syncthreads();
  vm = fmaxf(fmaxf(red[0], red[1]), fmaxf(red[2], red[3]));
  float e[8], s = 0.f;
#pragma unroll
  for (int j = 0; j < 8; j++) { e[j] = __expf(f[j] - vm); s += e[j]; }
#pragma unroll
  for (int o = 32; o > 0; o >>= 1) s += __shfl_xor(s, o);
  __syncthreads();
  if ((t & 63) == 0) red[wid] = s;
  __syncthreads();
  s = red[0] + red[1] + red[2] + red[3];
  const float rs = 1.0f / s;  // 1/32 applied in PV epilogue
  f16x8 ov;
#pragma unroll
  for (int j = 0; j < 8; j++) ov[j] = (f16)(e[j] * rs);
  *(f16x8*)(sr + t * 8) = ov;
}

// ========== 128x128xK GEMM, BK=32, dbuf 32KiB LDS, 4 waves, 4 blocks/CU ==========
// C = A[M][K] * B[N][K]^T. DT=0 bf16 MFMA (16x16x32), DT=1 f16 MFMA.
// LDS: L[buf2][A 128x32 | B 128x32] swizzled (R9-verified BK=32 scheme):
// logical (r,k) at elem r*32 + ((kslot ^ ((r>>1)&3))*8 + k&7); 16-lane read groups
// land <=2-way (free). Stage pre-swizzles GLOBAL col 8*((l&3)^((l>>3)&3)); gload_lds
// dest linear (rule 21 both-sides).
// Loop: STAGE(t+1) -> plain-C++ READS(t) -> 16 MFMA (compiler-interleaved) -> syncthreads.
// 4 independent blocks/CU fill each other's stage/barrier stalls (R8 mechanism, 2x).
// XCD-chunked L2 band raster (R12): bands of H m-rows sweep all n per XCD chunk.
template <int EPI, int DT>
__global__ __launch_bounds__(256, 4) void gemmdb_k(
    const bf16* __restrict__ Ab, const bf16* __restrict__ Bbp, void* __restrict__ Cb,
    const float* __restrict__ bias, const float* __restrict__ resid,
    int K, int lda, int ldb, int ldc, long astr, long bstr, long cstr) {
  extern __shared__ bf16 L[];  // 2 * 8192 elems = 32 KiB
  const int t = threadIdx.x;
  const int lane = t & 63;
  const int w = t >> 6;             // 0..3
  const int wm = w >> 1, wn = w & 1;

  // ---- XCD-chunked band raster (bijective; all grids: nwg%8==0, gx|cpx, H|R) ----
  const int gx = gridDim.x;                 // n tiles
  const int nwg = gx * gridDim.y;
  const int dd = blockIdx.y * gx + blockIdx.x;
  const int cpx = nwg >> 3;                 // tiles per XCD chunk
  const int xcd = dd & 7;                   // dispatch round-robins XCDs
  const int idx = dd >> 3;                  // 0..cpx-1 within chunk
  const int R = cpx / gx;                   // m-rows per chunk
  const int H = (R >= 8) ? 8 : R;           // band height (H | R for all our grids)
  const int bandsz = H * gx;
  const int bnd = idx / bandsz;
  const int rr = idx % bandsz;
  const int m_t = xcd * R + bnd * H + (rr % H);
  const int n_t = rr / H;
  const int m0 = m_t * 128;
  const int n0 = n_t * 128;

  const long z = blockIdx.z;
  const bf16* A;
  if constexpr (EPI == EPI_AOS) {
    A = (z < 4 ? Ab + z * astr : (const bf16*)bias + (z - 4) * astr);
  } else if constexpr (EPI == EPI_RESID) {
    const long qo[4] = {0, 33554432, 50331648, 67108864};  // h quarters (elem offs)
    A = Ab + qo[m0 >> 12] - (long)(m0 & ~4095) * lda;
  } else {
    A = Ab + z * astr;
  }
  const bf16* Bp = Bbp + z * bstr;

  // staging: chunk = 16 rows x 32k = 1KB; A,B each 8 chunks; wave w stages A,B chunks
  // 2w,2w+1. lane l -> row l>>2, kslot l&3; pre-swizzled source col 8*((l&3)^((l>>3)&3)).
  const int lrow = lane >> 2;
  const int sc = 8 * ((lane & 3) ^ ((lane >> 3) & 3));
  const bf16* gA[2];
  const bf16* gB[2];
#pragma unroll
  for (int j = 0; j < 2; ++j) {
    gA[j] = A + (long)(m0 + (w * 2 + j) * 16 + lrow) * lda + sc;
    gB[j] = Bp + (long)(n0 + (w * 2 + j) * 16 + lrow) * ldb + sc;
  }

#define STAGE(buf, tau)                                                          \
  do {                                                                           \
    _Pragma("unroll") for (int j_ = 0; j_ < 2; ++j_)                             \
        gload16(gA[j_] + (long)(tau) * 32,                                       \
                &L[(buf)*8192 + (w * 2 + j_) * 512]);                            \
    _Pragma("unroll") for (int j_ = 0; j_ < 2; ++j_)                             \
        gload16(gB[j_] + (long)(tau) * 32,                                       \
                &L[(buf)*8192 + 4096 + (w * 2 + j_) * 512]);                     \
  } while (0)

  // fragment reads: A rows wm*64+q*16+rA, B rows wn*64+p*16+rA; 8 plain b128 per K-32
  const int rA = lane & 15;
  const int kk0 = (lane >> 4) * 8;        // k-slot = lane>>4 in 0..3
  const int xorv = ((rA >> 1) & 3) * 8;   // BK=32 swizzle (R9-verified, 0 conflicts)

#define READ_ALL(base)                                                           \
  _Pragma("unroll") for (int q_ = 0; q_ < 4; ++q_) {                             \
    a[q_] = *(const bf16x8*)&L[(base) + (wm * 64 + q_ * 16 + rA) * 32 +          \
                               (kk0 ^ xorv)];                                    \
    b[q_] = *(const bf16x8*)&L[(base) + 4096 + (wn * 64 + q_ * 16 + rA) * 32 +   \
                               (kk0 ^ xorv)];                                    \
  }
#define MM(av, bv, cv)                                                           \
  (DT ? __builtin_amdgcn_mfma_f32_16x16x32_f16(                                  \
            __builtin_bit_cast(f16x8, av), __builtin_bit_cast(f16x8, bv), cv,    \
            0, 0, 0)                                                             \
      : __builtin_amdgcn_mfma_f32_16x16x32_bf16(av, bv, cv, 0, 0, 0))

  f32x4 acc[4][4] = {};
  bf16x8 a[4], b[4];

  // prologue: stage tile 0 into buf0
  STAGE(0, 0);
  __syncthreads();

  const int NT = K >> 5;
  for (int tt = 0; tt < NT; ++tt) {
    const int cur = tt & 1;
    const int base = cur * 8192;
    const bool nf = (tt + 1 < NT);
    if (nf) STAGE(cur ^ 1, tt + 1);
    READ_ALL(base);
    SETP(1);
#pragma unroll
    for (int q = 0; q < 4; ++q)
#pragma unroll
      for (int p = 0; p < 4; ++p)
        acc[q][p] = MM(a[q], b[p], acc[q][p]);
    SETP(0);
    __syncthreads();  // vmcnt(0)+lgkmcnt(0)+barrier: stage(t+1) visible, reads drained
  }

  // epilogue: C/D layout col=lane&15, row=(lane>>4)*4+j
  const int row0 = m0 + wm * 64;
  const int col0 = n0 + wn * 64;
  const int cl = lane & 15;
  const int rg = (lane >> 4) * 4;
#pragma unroll
  for (int mi = 0; mi < 4; mi++) {
#pragma unroll
    for (int ni = 0; ni < 4; ni++) {
#pragma unroll
      for (int j = 0; j < 4; j++) {
        const long gm = row0 + mi * 16 + rg + j;
        const int gn = col0 + ni * 16 + cl;
        float val = acc[mi][ni][j];
        if constexpr (EPI == EPI_QKV) {
          if (z < 2) {
            ((bf16*)Cb)[z * cstr + gm * ldc + gn] = (bf16)val;   // q,k bf16
          } else {
            ((f16*)resid)[gm * (long)ldc + gn] = (f16)val;       // v rows fp16
          }
        } else if constexpr (EPI == EPI_F16) {
          ((f16*)Cb)[z * cstr + gm * ldc + gn] = (f16)val;
        } else if constexpr (EPI == EPI_AOS) {
          ((bf16*)Cb)[z * cstr + gm * ldc + gn] = (bf16)(val * 0.03125f);
        } else if constexpr (EPI == EPI_SWISH) {
          const long qoc[4] = {0, 33554432, 50331648, 67108864};
          bf16* hq = (bf16*)Cb + qoc[m0 >> 12];
          float hv = val + bias[gn];
          hq[(long)(gm & 4095) * ldc + gn] = (bf16)(hv / (1.0f + __expf(-hv)));
        } else {  // EPI_RESID
          ((float*)Cb)[gm * (long)ldc + gn] = val + bias[gn] + resid[gm * (long)ldc + gn];
        }
      }
    }
  }
#undef STAGE
#undef READ_ALL
#undef MM
}

extern "C" void kernel_launch(void* const* d_in, const int* in_sizes, int n_in,
                              void* d_out, int out_size, void* d_ws, size_t ws_size,
                              hipStream_t stream) {
  const float* x  = (const float*)d_in[0];
  const float* g  = (const float*)d_in[1];
  const float* be = (const float*)d_in[2];
  const float* Wq = (const float*)d_in[3];
  const float* Wk = (const float*)d_in[4];
  const float* Wv = (const float*)d_in[5];
  const float* W1 = (const float*)d_in[6];
  const float* b1 = (const float*)d_in[7];
  const float* W2 = (const float*)d_in[8];
  const float* b2 = (const float*)d_in[9];

  hipFuncSetAttribute((const void*)&gemmdb_k<EPI_QKV, 0>,
                      hipFuncAttributeMaxDynamicSharedMemorySize, 32768);
  hipFuncSetAttribute((const void*)&gemmdb_k<EPI_F16, 0>,
                      hipFuncAttributeMaxDynamicSharedMemorySize, 32768);
  hipFuncSetAttribute((const void*)&gemmdb_k<EPI_AOS, 1>,
                      hipFuncAttributeMaxDynamicSharedMemorySize, 32768);
  hipFuncSetAttribute((const void*)&gemmdb_k<EPI_SWISH, 0>,
                      hipFuncAttributeMaxDynamicSharedMemorySize, 32768);
  hipFuncSetAttribute((const void*)&gemmdb_k<EPI_RESID, 0>,
                      hipFuncAttributeMaxDynamicSharedMemorySize, 32768);

  // ---- workspace overlay (bytes); identical to R6/R8/R11/R12 ----
  char* ws = (char*)d_ws;
  bf16* xn        = (bf16*)(ws + 0);
  f16*  scores_lo = (f16*)(ws + 0);            // z=0..3 after xn dies
  bf16* q         = (bf16*)(ws + 33554432);
  bf16* ao        = (bf16*)(ws + 33554432);    // after q dies
  bf16* kk        = (bf16*)(ws + 67108864);
  f16*  vT        = (f16*)(ws + 100663296);
  f16*  vrows     = (f16*)(ws + 134217728);
  f16*  scores_hi = (f16*)(ws + 134217728);    // z=4..7 after vrows dies
  bf16* wqT       = (bf16*)(ws + 167772160);
  bf16* w1T       = (bf16*)(ws + 174063616);
  bf16* w2T       = (bf16*)(ws + 182452224);
  // h quarters at byte offsets {0, 67108864, 100663296, 134217728} (EPI_SWISH/RESID).

  tcast_k<<<dim3(32, 32), 256, 0, stream>>>(Wq, wqT, 1024, 1024);
  tcast_k<<<dim3(32, 32), 256, 0, stream>>>(Wk, wqT + 1048576, 1024, 1024);
  tcast_k<<<dim3(32, 32), 256, 0, stream>>>(Wv, wqT + 2097152, 1024, 1024);
  tcast_k<<<dim3(128, 32), 256, 0, stream>>>(W1, w1T, 1024, 4096);
  tcast_k<<<dim3(32, 128), 256, 0, stream>>>(W2, w2T, 4096, 1024);

  ln_k<<<16384, 256, 0, stream>>>(x, g, be, xn);

  // QKV: z=0,1 -> q,k bf16; z=2 -> v rows fp16 via resid ptr
  gemmdb_k<EPI_QKV, 0><<<dim3(8, 128, 3), 256, 32768, stream>>>(
      xn, wqT, q, nullptr, (const float*)vrows, 1024, 1024, 1024, 1024,
      0L, 1048576L, 16777216L);

  tbf16_k<<<dim3(16, 32, 8), 256, 0, stream>>>(vrows, vT);

  // scores: two fp16 slabs
  gemmdb_k<EPI_F16, 0><<<dim3(16, 16, 4), 256, 32768, stream>>>(
      q, kk, scores_lo, nullptr, nullptr,
      1024, 1024, 1024, 2048, 2097152L, 2097152L, 4194304L);
  gemmdb_k<EPI_F16, 0><<<dim3(16, 16, 4), 256, 32768, stream>>>(
      q + 4L * 2097152, kk + 4L * 2097152, scores_hi, nullptr, nullptr,
      1024, 1024, 1024, 2048, 2097152L, 2097152L, 4194304L);

  softmax16_k<<<16384, 256, 0, stream>>>(scores_lo, scores_hi);

  // PV: single launch over all 8 batches; A slab-split inside kernel (f16 MFMA)
  gemmdb_k<EPI_AOS, 1><<<dim3(8, 16, 8), 256, 32768, stream>>>(
      (const bf16*)scores_lo, (const bf16*)vT, ao, (const float*)scores_hi, nullptr,
      2048, 2048, 2048, 1024, 4194304L, 2097152L, 2097152L);

  // MLP1: h (quartered) = swish(ao @ W1 + b1)
  gemmdb_k<EPI_SWISH, 0><<<dim3(32, 128, 1), 256, 32768, stream>>>(
      ao, w1T, ws, b1, nullptr, 1024, 1024, 1024, 4096, 0L, 0L, 0L);
  // MLP2: out = h @ W2 + b2 + x (A from h quarters)
  gemmdb_k<EPI_RESID, 0><<<dim3(8, 128, 1), 256, 32768, stream>>>(
      (const bf16*)ws, w2T, d_out, b2, x, 4096, 4096, 4096, 1024, 0L, 0L, 0L);
}

// Round 15
// 589.614 us; speedup vs baseline: 1.1946x; 1.1823x over previous
//
#include <hip/hip_runtime.h>

// EncoderBlock: B=8, S=2048, D=1024, H=4096, single-head attn (scale AFTER softmax),
// LN -> QKV -> scores -> softmax*(1/32) -> PV -> MLP(Swish) -> +residual.
// Round 15: R12 base (594us best) + ONE change: counted-vmcnt 2-deep pipeline.
// The per-iter __syncthreads() vmcnt(0) drained the FULL staging latency each K-tile
// (m233: stage+drain = ~72% of 2-phase critical path). Now: raw fence-wrapped
// s_barrier + vmcnt(8) (counted: own stage-t landed, stage-t+1's 8 loads in flight);
// stage(t+2) issues a full tile before consumption. No vmcnt(0) in main loop.
// Everything else (BK=64 dbuf, 2 blk/CU, band raster, plain reads) = R12 verbatim.
// WS = 190,840,832 B, overlay identical to R6/R8/R11/R12.

#define Bb_ 8
#define Ss_ 2048
#define Dd_ 1024
#define Hh_ 4096

typedef __bf16 bf16;
typedef _Float16 f16;
typedef __attribute__((ext_vector_type(8))) __bf16 bf16x8;
typedef __attribute__((ext_vector_type(8))) _Float16 f16x8;
typedef __attribute__((ext_vector_type(4))) __bf16 bf16x4;
typedef __attribute__((ext_vector_type(4))) float f32x4;

enum { EPI_QKV = 0, EPI_F16 = 1, EPI_AOS = 2, EPI_SWISH = 3, EPI_RESID = 4 };

__device__ __forceinline__ void gload16(const bf16* g, bf16* l) {
  __builtin_amdgcn_global_load_lds(
      (const __attribute__((address_space(1))) void*)g,
      (__attribute__((address_space(3))) void*)l, 16, 0, 0);
}

#define SETP(x) __builtin_amdgcn_s_setprio(x)
// fence-wrapped barrier: compiler may not move LDS/global ops across it (runtime-free)
#define BARRIER()                          \
  do {                                     \
    asm volatile("" ::: "memory");         \
    __builtin_amdgcn_s_barrier();          \
    asm volatile("" ::: "memory");         \
  } while (0)
#define VMC(n) asm volatile("s_waitcnt vmcnt(" #n ")" ::: "memory")

// ---------- transpose-cast: W[K][N] f32 -> WT[N][K] bf16 ----------
__global__ __launch_bounds__(256) void tcast_k(const float* __restrict__ W,
                                               bf16* __restrict__ WT, int K, int N) {
  __shared__ float tile[32][33];
  const int tn0 = blockIdx.x * 32;
  const int tk0 = blockIdx.y * 32;
  const int t = threadIdx.x;
  const int c = t & 31;
  const int r4 = t >> 5;
#pragma unroll
  for (int i = 0; i < 4; i++) {
    int r = r4 + i * 8;
    tile[r][c] = W[(long)(tk0 + r) * N + (tn0 + c)];
  }
  __syncthreads();
#pragma unroll
  for (int i = 0; i < 4; i++) {
    int r = r4 + i * 8;
    WT[(long)(tn0 + r) * K + (tk0 + c)] = (bf16)tile[c][r];
  }
}

// ---------- fp16 transpose: v[z][2048][1024] -> vT[z][1024][2048] ----------
__global__ __launch_bounds__(256) void tbf16_k(const f16* __restrict__ V,
                                               f16* __restrict__ VT) {
  __shared__ f16 tile[64][72];
  const long z = blockIdx.z;
  const int n0 = blockIdx.x * 64;
  const int k0 = blockIdx.y * 64;
  const int t = threadIdx.x;
  const int r = t >> 3;
  const int c = (t & 7) * 8;
  const f16* Vb = V + z * (long)(Ss_ * Dd_);
  f16* VTb = VT + z * (long)(Dd_ * Ss_);
#pragma unroll
  for (int i = 0; i < 2; i++)
    *(f16x8*)&tile[r + i * 32][c] =
        *(const f16x8*)(Vb + (long)(k0 + r + i * 32) * Dd_ + n0 + c);
  __syncthreads();
#pragma unroll
  for (int i = 0; i < 2; i++) {
    const int n = r + i * 32;
    f16x8 ov;
#pragma unroll
    for (int j = 0; j < 8; j++) ov[j] = tile[c + j][n];
    *(f16x8*)(VTb + (long)(n0 + n) * Ss_ + k0 + c) = ov;
  }
}

// ---------- LayerNorm: x[row][1024] f32 -> xn bf16 ----------
__global__ __launch_bounds__(256) void ln_k(const float* __restrict__ x,
                                            const float* __restrict__ gamma,
                                            const float* __restrict__ beta,
                                            bf16* __restrict__ xn) {
  const long row = blockIdx.x;
  const float* xr = x + row * Dd_;
  const int t = threadIdx.x;
  float4 v = *(const float4*)(xr + t * 4);
  float s = v.x + v.y + v.z + v.w;
  float sq = v.x * v.x + v.y * v.y + v.z * v.z + v.w * v.w;
#pragma unroll
  for (int o = 32; o > 0; o >>= 1) {
    s += __shfl_down(s, o);
    sq += __shfl_down(sq, o);
  }
  __shared__ float ls[4], lq[4];
  const int wid = t >> 6;
  if ((t & 63) == 0) { ls[wid] = s; lq[wid] = sq; }
  __syncthreads();
  if (t == 0) {
    float S = ls[0] + ls[1] + ls[2] + ls[3];
    float Q = lq[0] + lq[1] + lq[2] + lq[3];
    float mu = S * (1.0f / Dd_);
    float var = Q * (1.0f / Dd_) - mu * mu;
    ls[0] = mu;
    lq[0] = rsqrtf(var + 1e-5f);
  }
  __syncthreads();
  const float mu = ls[0], rstd = lq[0];
  float4 g = *(const float4*)(gamma + t * 4);
  float4 be = *(const float4*)(beta + t * 4);
  bf16x4 ov;
  ov[0] = (bf16)((v.x - mu) * rstd * g.x + be.x);
  ov[1] = (bf16)((v.y - mu) * rstd * g.y + be.y);
  ov[2] = (bf16)((v.z - mu) * rstd * g.z + be.z);
  ov[3] = (bf16)((v.w - mu) * rstd * g.w + be.w);
  *(bf16x4*)(xn + row * Dd_ + t * 4) = ov;
}

// ---------- softmax: fp16 scores (two slabs) -> fp16 probs (UNSCALED), in place ----------
__global__ __launch_bounds__(256) void softmax16_k(f16* __restrict__ lo,
                                                   f16* __restrict__ hi) {
  const long row = blockIdx.x;
  const long z = row >> 11;
  f16* sr = (z < 4 ? lo + z * 4194304L : hi + (z - 4) * 4194304L) +
            (row & 2047) * (long)Ss_;
  const int t = threadIdx.x;
  f16x8 v = *(const f16x8*)(sr + t * 8);
  float f[8];
#pragma unroll
  for (int j = 0; j < 8; j++) f[j] = (float)v[j];
  float vm = f[0];
#pragma unroll
  for (int j = 1; j < 8; j++) vm = fmaxf(vm, f[j]);
  __shared__ float red[4];
#pragma unroll
  for (int o = 32; o > 0; o >>= 1) vm = fmaxf(vm, __shfl_xor(vm, o));
  const int wid = t >> 6;
  if ((t & 63) == 0) red[wid] = vm;
  __syncthreads();
  vm = fmaxf(fmaxf(red[0], red[1]), fmaxf(red[2], red[3]));
  float e[8], s = 0.f;
#pragma unroll
  for (int j = 0; j < 8; j++) { e[j] = __expf(f[j] - vm); s += e[j]; }
#pragma unroll
  for (int o = 32; o > 0; o >>= 1) s += __shfl_xor(s, o);
  __syncthreads();
  if ((t & 63) == 0) red[wid] = s;
  __syncthreads();
  s = red[0] + red[1] + red[2] + red[3];
  const float rs = 1.0f / s;  // 1/32 applied in PV epilogue
  f16x8 ov;
#pragma unroll
  for (int j = 0; j < 8; j++) ov[j] = (f16)(e[j] * rs);
  *(f16x8*)(sr + t * 8) = ov;
}

// ========== 128x128xK GEMM, BK=64, dbuf 64KiB LDS, 4 waves, 2 blocks/CU ==========
// C = A[M][K] * B[N][K]^T. DT=0 bf16 MFMA (16x16x32), DT=1 f16 MFMA.
// LDS: L[buf2][op2][128*64] swizzled: (r,k) at elem r*64 + (k ^ ((r&7)*8));
// staged via pre-swizzled GLOBAL source + linear gload_lds dest (rule 21).
// R15 pipeline (2 K-tiles per loop iter, 2-deep prefetch, counted vmcnt):
//   prologue: STAGE(buf0,0); STAGE(buf1,1)            [16 loads in flight]
//   loop (tt += 2):
//     VMC(8); BARRIER();        // own stage(tt) landed; BAR -> ALL waves' chunks landed
//     READS(buf0,tt); MFMA      // compiler-managed lgkmcnt
//     BARRIER();                // all waves done reading buf0
//     STAGE(buf0,tt+2)          // overwrite safe; latency window ~1 full tile
//     VMC(8); BARRIER();        // stage(tt+1) landed (8 newer = stage tt+2)
//     READS(buf1,tt+1); MFMA
//     BARRIER();
//     STAGE(buf1,tt+3)
// NT even for all dispatches (16/16/32/16/64). No vmcnt(0) in the main loop.
// XCD-chunked L2 band raster (R12): bands of H m-rows sweep all n per XCD chunk.
template <int EPI, int DT>
__global__ __launch_bounds__(256, 2) void gemmdb_k(
    const bf16* __restrict__ Ab, const bf16* __restrict__ Bbp, void* __restrict__ Cb,
    const float* __restrict__ bias, const float* __restrict__ resid,
    int K, int lda, int ldb, int ldc, long astr, long bstr, long cstr) {
  extern __shared__ bf16 L[];  // 2*2*8192 elems = 64 KiB
  const int t = threadIdx.x;
  const int lane = t & 63;
  const int w = t >> 6;             // 0..3
  const int wm = w >> 1, wn = w & 1;

  // ---- XCD-chunked band raster (bijective; all grids: nwg%8==0, gx|cpx, H|R) ----
  const int gx = gridDim.x;                 // n tiles
  const int nwg = gx * gridDim.y;
  const int dd = blockIdx.y * gx + blockIdx.x;
  const int cpx = nwg >> 3;                 // tiles per XCD chunk
  const int xcd = dd & 7;                   // dispatch round-robins XCDs
  const int idx = dd >> 3;                  // 0..cpx-1 within chunk
  const int R = cpx / gx;                   // m-rows per chunk
  const int H = (R >= 8) ? 8 : R;           // band height (H | R for all our grids)
  const int bandsz = H * gx;
  const int bnd = idx / bandsz;
  const int rr = idx % bandsz;
  const int m_t = xcd * R + bnd * H + (rr % H);
  const int n_t = rr / H;
  const int m0 = m_t * 128;
  const int n0 = n_t * 128;

  const long z = blockIdx.z;
  const bf16* A;
  if constexpr (EPI == EPI_AOS) {
    A = (z < 4 ? Ab + z * astr : (const bf16*)bias + (z - 4) * astr);
  } else if constexpr (EPI == EPI_RESID) {
    const long qo[4] = {0, 33554432, 50331648, 67108864};  // h quarters (elem offs)
    A = Ab + qo[m0 >> 12] - (long)(m0 & ~4095) * lda;
  } else {
    A = Ab + z * astr;
  }
  const bf16* Bp = Bbp + z * bstr;

  // staging: 128 rows -> 16 chunks of 8 rows (1KB each); wave w stages A,B chunks 4w..4w+3.
  // lane l -> row chunk*8 + (l>>3); pre-swizzled source col = 8*((l&7)^(l>>3)).
  const int lrow = lane >> 3;
  const int sc = 8 * ((lane & 7) ^ lrow);
  const bf16* gA[4];
  const bf16* gB[4];
#pragma unroll
  for (int j = 0; j < 4; ++j) {
    const int r = (w * 4 + j) * 8 + lrow;
    gA[j] = A + (long)(m0 + r) * lda + sc;
    gB[j] = Bp + (long)(n0 + r) * ldb + sc;
  }

#define STAGE(buf, tau)                                                          \
  do {                                                                           \
    _Pragma("unroll") for (int j_ = 0; j_ < 4; ++j_)                             \
        gload16(gA[j_] + (long)(tau) * 64,                                       \
                &L[((buf)*2 + 0) * 8192 + (w * 4 + j_) * 512]);                  \
    _Pragma("unroll") for (int j_ = 0; j_ < 4; ++j_)                             \
        gload16(gB[j_] + (long)(tau) * 64,                                       \
                &L[((buf)*2 + 1) * 8192 + (w * 4 + j_) * 512]);                  \
  } while (0)

  // fragment reads: A rows wm*64.., B rows wn*64..; 16 plain b128 reads per K-tile
  const int rA = lane & 15;
  const int kk0 = (lane >> 4) * 8;
  const int xorv = (rA & 7) * 8;

#define READ_ALL(ab, bb)                                                         \
  _Pragma("unroll") for (int q_ = 0; q_ < 4; ++q_)                               \
  _Pragma("unroll") for (int ks_ = 0; ks_ < 2; ++ks_) {                          \
    a[q_][ks_] = *(const bf16x8*)&L[(ab) + (wm * 64 + q_ * 16 + rA) * 64 +       \
                                    ((ks_ * 32 + kk0) ^ xorv)];                  \
    b[q_][ks_] = *(const bf16x8*)&L[(bb) + (wn * 64 + q_ * 16 + rA) * 64 +       \
                                    ((ks_ * 32 + kk0) ^ xorv)];                  \
  }
#define MM(av, bv, cv)                                                           \
  (DT ? __builtin_amdgcn_mfma_f32_16x16x32_f16(                                  \
            __builtin_bit_cast(f16x8, av), __builtin_bit_cast(f16x8, bv), cv,    \
            0, 0, 0)                                                             \
      : __builtin_amdgcn_mfma_f32_16x16x32_bf16(av, bv, cv, 0, 0, 0))
#define MFMA_ALL()                                                               \
  do {                                                                           \
    SETP(1);                                                                     \
    _Pragma("unroll") for (int ks = 0; ks < 2; ++ks)                             \
    _Pragma("unroll") for (int q = 0; q < 4; ++q)                                \
    _Pragma("unroll") for (int p = 0; p < 4; ++p)                                \
        acc[q][p] = MM(a[q][ks], b[p][ks], acc[q][p]);                           \
    SETP(0);                                                                     \
  } while (0)

  f32x4 acc[4][4] = {};
  bf16x8 a[4][2], b[4][2];

  // prologue: 2-deep prefetch (16 loads in flight)
  STAGE(0, 0);
  STAGE(1, 1);

  const int NT = K >> 6;  // even for all dispatches
  for (int tt = 0; tt < NT; tt += 2) {
    // --- K-tile tt (buf0) ---
    VMC(8);      // own stage(tt) landed (8 newer = own stage(tt+1))
    BARRIER();   // all waves' stage(tt) chunks landed
    READ_ALL(0 * 16384, 0 * 16384 + 8192);
    MFMA_ALL();
    BARRIER();   // all waves finished reading buf0 (lgkmcnt before MFMA use)
    if (tt + 2 < NT) STAGE(0, tt + 2);
    // --- K-tile tt+1 (buf1) ---
    VMC(8);      // own stage(tt+1) landed (8 newer = own stage(tt+2))
    BARRIER();
    READ_ALL(1 * 16384, 1 * 16384 + 8192);
    MFMA_ALL();
    BARRIER();
    if (tt + 3 < NT) STAGE(1, tt + 3);
  }

  // epilogue: C/D layout col=lane&15, row=(lane>>4)*4+j
  const int row0 = m0 + wm * 64;
  const int col0 = n0 + wn * 64;
  const int cl = lane & 15;
  const int rg = (lane >> 4) * 4;
#pragma unroll
  for (int mi = 0; mi < 4; mi++) {
#pragma unroll
    for (int ni = 0; ni < 4; ni++) {
#pragma unroll
      for (int j = 0; j < 4; j++) {
        const long gm = row0 + mi * 16 + rg + j;
        const int gn = col0 + ni * 16 + cl;
        float val = acc[mi][ni][j];
        if constexpr (EPI == EPI_QKV) {
          if (z < 2) {
            ((bf16*)Cb)[z * cstr + gm * ldc + gn] = (bf16)val;   // q,k bf16
          } else {
            ((f16*)resid)[gm * (long)ldc + gn] = (f16)val;       // v rows fp16
          }
        } else if constexpr (EPI == EPI_F16) {
          ((f16*)Cb)[z * cstr + gm * ldc + gn] = (f16)val;
        } else if constexpr (EPI == EPI_AOS) {
          ((bf16*)Cb)[z * cstr + gm * ldc + gn] = (bf16)(val * 0.03125f);
        } else if constexpr (EPI == EPI_SWISH) {
          const long qoc[4] = {0, 33554432, 50331648, 67108864};
          bf16* hq = (bf16*)Cb + qoc[m0 >> 12];
          float hv = val + bias[gn];
          hq[(long)(gm & 4095) * ldc + gn] = (bf16)(hv / (1.0f + __expf(-hv)));
        } else {  // EPI_RESID
          ((float*)Cb)[gm * (long)ldc + gn] = val + bias[gn] + resid[gm * (long)ldc + gn];
        }
      }
    }
  }
#undef STAGE
#undef READ_ALL
#undef MM
#undef MFMA_ALL
}

extern "C" void kernel_launch(void* const* d_in, const int* in_sizes, int n_in,
                              void* d_out, int out_size, void* d_ws, size_t ws_size,
                              hipStream_t stream) {
  const float* x  = (const float*)d_in[0];
  const float* g  = (const float*)d_in[1];
  const float* be = (const float*)d_in[2];
  const float* Wq = (const float*)d_in[3];
  const float* Wk = (const float*)d_in[4];
  const float* Wv = (const float*)d_in[5];
  const float* W1 = (const float*)d_in[6];
  const float* b1 = (const float*)d_in[7];
  const float* W2 = (const float*)d_in[8];
  const float* b2 = (const float*)d_in[9];

  hipFuncSetAttribute((const void*)&gemmdb_k<EPI_QKV, 0>,
                      hipFuncAttributeMaxDynamicSharedMemorySize, 65536);
  hipFuncSetAttribute((const void*)&gemmdb_k<EPI_F16, 0>,
                      hipFuncAttributeMaxDynamicSharedMemorySize, 65536);
  hipFuncSetAttribute((const void*)&gemmdb_k<EPI_AOS, 1>,
                      hipFuncAttributeMaxDynamicSharedMemorySize, 65536);
  hipFuncSetAttribute((const void*)&gemmdb_k<EPI_SWISH, 0>,
                      hipFuncAttributeMaxDynamicSharedMemorySize, 65536);
  hipFuncSetAttribute((const void*)&gemmdb_k<EPI_RESID, 0>,
                      hipFuncAttributeMaxDynamicSharedMemorySize, 65536);

  // ---- workspace overlay (bytes); identical to R6/R8/R11/R12 ----
  char* ws = (char*)d_ws;
  bf16* xn        = (bf16*)(ws + 0);
  f16*  scores_lo = (f16*)(ws + 0);            // z=0..3 after xn dies
  bf16* q         = (bf16*)(ws + 33554432);
  bf16* ao        = (bf16*)(ws + 33554432);    // after q dies
  bf16* kk        = (bf16*)(ws + 67108864);
  f16*  vT        = (f16*)(ws + 100663296);
  f16*  vrows     = (f16*)(ws + 134217728);
  f16*  scores_hi = (f16*)(ws + 134217728);    // z=4..7 after vrows dies
  bf16* wqT       = (bf16*)(ws + 167772160);
  bf16* w1T       = (bf16*)(ws + 174063616);
  bf16* w2T       = (bf16*)(ws + 182452224);
  // h quarters at byte offsets {0, 67108864, 100663296, 134217728} (EPI_SWISH/RESID).

  tcast_k<<<dim3(32, 32), 256, 0, stream>>>(Wq, wqT, 1024, 1024);
  tcast_k<<<dim3(32, 32), 256, 0, stream>>>(Wk, wqT + 1048576, 1024, 1024);
  tcast_k<<<dim3(32, 32), 256, 0, stream>>>(Wv, wqT + 2097152, 1024, 1024);
  tcast_k<<<dim3(128, 32), 256, 0, stream>>>(W1, w1T, 1024, 4096);
  tcast_k<<<dim3(32, 128), 256, 0, stream>>>(W2, w2T, 4096, 1024);

  ln_k<<<16384, 256, 0, stream>>>(x, g, be, xn);

  // QKV: z=0,1 -> q,k bf16; z=2 -> v rows fp16 via resid ptr
  gemmdb_k<EPI_QKV, 0><<<dim3(8, 128, 3), 256, 65536, stream>>>(
      xn, wqT, q, nullptr, (const float*)vrows, 1024, 1024, 1024, 1024,
      0L, 1048576L, 16777216L);

  tbf16_k<<<dim3(16, 32, 8), 256, 0, stream>>>(vrows, vT);

  // scores: two fp16 slabs
  gemmdb_k<EPI_F16, 0><<<dim3(16, 16, 4), 256, 65536, stream>>>(
      q, kk, scores_lo, nullptr, nullptr,
      1024, 1024, 1024, 2048, 2097152L, 2097152L, 4194304L);
  gemmdb_k<EPI_F16, 0><<<dim3(16, 16, 4), 256, 65536, stream>>>(
      q + 4L * 2097152, kk + 4L * 2097152, scores_hi, nullptr, nullptr,
      1024, 1024, 1024, 2048, 2097152L, 2097152L, 4194304L);

  softmax16_k<<<16384, 256, 0, stream>>>(scores_lo, scores_hi);

  // PV: single launch over all 8 batches; A slab-split inside kernel (f16 MFMA)
  gemmdb_k<EPI_AOS, 1><<<dim3(8, 16, 8), 256, 65536, stream>>>(
      (const bf16*)scores_lo, (const bf16*)vT, ao, (const float*)scores_hi, nullptr,
      2048, 2048, 2048, 1024, 4194304L, 2097152L, 2097152L);

  // MLP1: h (quartered) = swish(ao @ W1 + b1)
  gemmdb_k<EPI_SWISH, 0><<<dim3(32, 128, 1), 256, 65536, stream>>>(
      ao, w1T, ws, b1, nullptr, 1024, 1024, 1024, 4096, 0L, 0L, 0L);
  // MLP2: out = h @ W2 + b2 + x (A from h quarters)
  gemmdb_k<EPI_RESID, 0><<<dim3(8, 128, 1), 256, 65536, stream>>>(
      (const bf16*)ws, w2T, d_out, b2, x, 4096, 4096, 4096, 1024, 0L, 0L, 0L);
}

// Round 16
// 543.737 us; speedup vs baseline: 1.2954x; 1.0844x over previous
//
#include <hip/hip_runtime.h>
#include <hip/hip_fp8.h>

// EncoderBlock: B=8, S=2048, D=1024, H=4096, single-head attn (scale AFTER softmax),
// LN -> QKV -> scores -> softmax*(1/32) -> PV -> MLP(Swish) -> +residual.
// Round 16: R15 base (589us) + fp8 e4m3 MLP path. ao/w1T/w2T/h stored fp8; new
// gemmq_k (1-byte elems, 32KiB dbuf, ds_read_b64 frags, mfma fp8_fp8) runs MLP1/MLP2.
// Staging bytes + FETCH halve (m145: +9% at this structure class from bytes alone).
// bf16/f16 kernels (QKV/scores/PV) untouched except PV epilogue writes fp8 ao.
// WS = 190,840,832 B; overlay as R6/R8 with h quarters now fp8 (same byte offsets).

#define Bb_ 8
#define Ss_ 2048
#define Dd_ 1024
#define Hh_ 4096

typedef __bf16 bf16;
typedef _Float16 f16;
typedef unsigned char u8;
typedef unsigned long long u64;
typedef __attribute__((ext_vector_type(8))) __bf16 bf16x8;
typedef __attribute__((ext_vector_type(8))) _Float16 f16x8;
typedef __attribute__((ext_vector_type(4))) __bf16 bf16x4;
typedef __attribute__((ext_vector_type(4))) float f32x4;

enum { EPI_QKV = 0, EPI_F16 = 1, EPI_AOS = 2, EPI_SWISH = 3, EPI_RESID = 4 };

__device__ __forceinline__ void gload16(const void* g, void* l) {
  __builtin_amdgcn_global_load_lds(
      (const __attribute__((address_space(1))) void*)g,
      (__attribute__((address_space(3))) void*)l, 16, 0, 0);
}

__device__ __forceinline__ u8 to_fp8(float f) {
  __hip_fp8_e4m3 v(f);      // OCP e4m3fn (gfx950 native)
  return (u8)v.__x;
}

#define SETP(x) __builtin_amdgcn_s_setprio(x)
#define BARRIER()                          \
  do {                                     \
    asm volatile("" ::: "memory");         \
    __builtin_amdgcn_s_barrier();          \
    asm volatile("" ::: "memory");         \
  } while (0)
#define VMC(n) asm volatile("s_waitcnt vmcnt(" #n ")" ::: "memory")

// ---------- transpose-cast: W[K][N] f32 -> WT[N][K] bf16 ----------
__global__ __launch_bounds__(256) void tcast_k(const float* __restrict__ W,
                                               bf16* __restrict__ WT, int K, int N) {
  __shared__ float tile[32][33];
  const int tn0 = blockIdx.x * 32;
  const int tk0 = blockIdx.y * 32;
  const int t = threadIdx.x;
  const int c = t & 31;
  const int r4 = t >> 5;
#pragma unroll
  for (int i = 0; i < 4; i++) {
    int r = r4 + i * 8;
    tile[r][c] = W[(long)(tk0 + r) * N + (tn0 + c)];
  }
  __syncthreads();
#pragma unroll
  for (int i = 0; i < 4; i++) {
    int r = r4 + i * 8;
    WT[(long)(tn0 + r) * K + (tk0 + c)] = (bf16)tile[c][r];
  }
}

// ---------- transpose-cast: W[K][N] f32 -> WT[N][K] fp8 e4m3 ----------
__global__ __launch_bounds__(256) void tcast8_k(const float* __restrict__ W,
                                                u8* __restrict__ WT, int K, int N) {
  __shared__ float tile[32][33];
  const int tn0 = blockIdx.x * 32;
  const int tk0 = blockIdx.y * 32;
  const int t = threadIdx.x;
  const int c = t & 31;
  const int r4 = t >> 5;
#pragma unroll
  for (int i = 0; i < 4; i++) {
    int r = r4 + i * 8;
    tile[r][c] = W[(long)(tk0 + r) * N + (tn0 + c)];
  }
  __syncthreads();
#pragma unroll
  for (int i = 0; i < 4; i++) {
    int r = r4 + i * 8;
    WT[(long)(tn0 + r) * K + (tk0 + c)] = to_fp8(tile[c][r]);
  }
}

// ---------- fp16 transpose: v[z][2048][1024] -> vT[z][1024][2048] ----------
__global__ __launch_bounds__(256) void tbf16_k(const f16* __restrict__ V,
                                               f16* __restrict__ VT) {
  __shared__ f16 tile[64][72];
  const long z = blockIdx.z;
  const int n0 = blockIdx.x * 64;
  const int k0 = blockIdx.y * 64;
  const int t = threadIdx.x;
  const int r = t >> 3;
  const int c = (t & 7) * 8;
  const f16* Vb = V + z * (long)(Ss_ * Dd_);
  f16* VTb = VT + z * (long)(Dd_ * Ss_);
#pragma unroll
  for (int i = 0; i < 2; i++)
    *(f16x8*)&tile[r + i * 32][c] =
        *(const f16x8*)(Vb + (long)(k0 + r + i * 32) * Dd_ + n0 + c);
  __syncthreads();
#pragma unroll
  for (int i = 0; i < 2; i++) {
    const int n = r + i * 32;
    f16x8 ov;
#pragma unroll
    for (int j = 0; j < 8; j++) ov[j] = tile[c + j][n];
    *(f16x8*)(VTb + (long)(n0 + n) * Ss_ + k0 + c) = ov;
  }
}

// ---------- LayerNorm: x[row][1024] f32 -> xn bf16 ----------
__global__ __launch_bounds__(256) void ln_k(const float* __restrict__ x,
                                            const float* __restrict__ gamma,
                                            const float* __restrict__ beta,
                                            bf16* __restrict__ xn) {
  const long row = blockIdx.x;
  const float* xr = x + row * Dd_;
  const int t = threadIdx.x;
  float4 v = *(const float4*)(xr + t * 4);
  float s = v.x + v.y + v.z + v.w;
  float sq = v.x * v.x + v.y * v.y + v.z * v.z + v.w * v.w;
#pragma unroll
  for (int o = 32; o > 0; o >>= 1) {
    s += __shfl_down(s, o);
    sq += __shfl_down(sq, o);
  }
  __shared__ float ls[4], lq[4];
  const int wid = t >> 6;
  if ((t & 63) == 0) { ls[wid] = s; lq[wid] = sq; }
  __syncthreads();
  if (t == 0) {
    float S = ls[0] + ls[1] + ls[2] + ls[3];
    float Q = lq[0] + lq[1] + lq[2] + lq[3];
    float mu = S * (1.0f / Dd_);
    float var = Q * (1.0f / Dd_) - mu * mu;
    ls[0] = mu;
    lq[0] = rsqrtf(var + 1e-5f);
  }
  __syncthreads();
  const float mu = ls[0], rstd = lq[0];
  float4 g = *(const float4*)(gamma + t * 4);
  float4 be = *(const float4*)(beta + t * 4);
  bf16x4 ov;
  ov[0] = (bf16)((v.x - mu) * rstd * g.x + be.x);
  ov[1] = (bf16)((v.y - mu) * rstd * g.y + be.y);
  ov[2] = (bf16)((v.z - mu) * rstd * g.z + be.z);
  ov[3] = (bf16)((v.w - mu) * rstd * g.w + be.w);
  *(bf16x4*)(xn + row * Dd_ + t * 4) = ov;
}

// ---------- softmax: fp16 scores (two slabs) -> fp16 probs (UNSCALED), in place ----------
__global__ __launch_bounds__(256) void softmax16_k(f16* __restrict__ lo,
                                                   f16* __restrict__ hi) {
  const long row = blockIdx.x;
  const long z = row >> 11;
  f16* sr = (z < 4 ? lo + z * 4194304L : hi + (z - 4) * 4194304L) +
            (row & 2047) * (long)Ss_;
  const int t = threadIdx.x;
  f16x8 v = *(const f16x8*)(sr + t * 8);
  float f[8];
#pragma unroll
  for (int j = 0; j < 8; j++) f[j] = (float)v[j];
  float vm = f[0];
#pragma unroll
  for (int j = 1; j < 8; j++) vm = fmaxf(vm, f[j]);
  __shared__ float red[4];
#pragma unroll
  for (int o = 32; o > 0; o >>= 1) vm = fmaxf(vm, __shfl_xor(vm, o));
  const int wid = t >> 6;
  if ((t & 63) == 0) red[wid] = vm;
  __syncthreads();
  vm = fmaxf(fmaxf(red[0], red[1]), fmaxf(red[2], red[3]));
  float e[8], s = 0.f;
#pragma unroll
  for (int j = 0; j < 8; j++) { e[j] = __expf(f[j] - vm); s += e[j]; }
#pragma unroll
  for (int o = 32; o > 0; o >>= 1) s += __shfl_xor(s, o);
  __syncthreads();
  if ((t & 63) == 0) red[wid] = s;
  __syncthreads();
  s = red[0] + red[1] + red[2] + red[3];
  const float rs = 1.0f / s;  // 1/32 applied in PV epilogue
  f16x8 ov;
#pragma unroll
  for (int j = 0; j < 8; j++) ov[j] = (f16)(e[j] * rs);
  *(f16x8*)(sr + t * 8) = ov;
}

// ========== bf16/f16 128x128xK GEMM (R15 core): BK=64, dbuf 64KiB, 2 blk/CU =========
template <int EPI, int DT>
__global__ __launch_bounds__(256, 2) void gemmdb_k(
    const bf16* __restrict__ Ab, const bf16* __restrict__ Bbp, void* __restrict__ Cb,
    const float* __restrict__ bias, const float* __restrict__ resid,
    int K, int lda, int ldb, int ldc, long astr, long bstr, long cstr) {
  extern __shared__ bf16 L[];  // 2*2*8192 elems = 64 KiB
  const int t = threadIdx.x;
  const int lane = t & 63;
  const int w = t >> 6;
  const int wm = w >> 1, wn = w & 1;

  // XCD-chunked band raster (bijective; all grids: nwg%8==0, gx|cpx, H|R)
  const int gx = gridDim.x;
  const int nwg = gx * gridDim.y;
  const int dd = blockIdx.y * gx + blockIdx.x;
  const int cpx = nwg >> 3;
  const int xcd = dd & 7;
  const int idx = dd >> 3;
  const int R = cpx / gx;
  const int H = (R >= 8) ? 8 : R;
  const int bandsz = H * gx;
  const int bnd = idx / bandsz;
  const int rr = idx % bandsz;
  const int m_t = xcd * R + bnd * H + (rr % H);
  const int n_t = rr / H;
  const int m0 = m_t * 128;
  const int n0 = n_t * 128;

  const long z = blockIdx.z;
  const bf16* A;
  if constexpr (EPI == EPI_AOS) {
    A = (z < 4 ? Ab + z * astr : (const bf16*)bias + (z - 4) * astr);
  } else {
    A = Ab + z * astr;
  }
  const bf16* Bp = Bbp + z * bstr;

  const int lrow = lane >> 3;
  const int sc = 8 * ((lane & 7) ^ lrow);
  const bf16* gA[4];
  const bf16* gB[4];
#pragma unroll
  for (int j = 0; j < 4; ++j) {
    const int r = (w * 4 + j) * 8 + lrow;
    gA[j] = A + (long)(m0 + r) * lda + sc;
    gB[j] = Bp + (long)(n0 + r) * ldb + sc;
  }

#define STAGE(buf, tau)                                                          \
  do {                                                                           \
    _Pragma("unroll") for (int j_ = 0; j_ < 4; ++j_)                             \
        gload16(gA[j_] + (long)(tau) * 64,                                       \
                &L[((buf)*2 + 0) * 8192 + (w * 4 + j_) * 512]);                  \
    _Pragma("unroll") for (int j_ = 0; j_ < 4; ++j_)                             \
        gload16(gB[j_] + (long)(tau) * 64,                                       \
                &L[((buf)*2 + 1) * 8192 + (w * 4 + j_) * 512]);                  \
  } while (0)

  const int rA = lane & 15;
  const int kk0 = (lane >> 4) * 8;
  const int xorv = (rA & 7) * 8;

#define READ_ALL(ab, bb)                                                         \
  _Pragma("unroll") for (int q_ = 0; q_ < 4; ++q_)                               \
  _Pragma("unroll") for (int ks_ = 0; ks_ < 2; ++ks_) {                          \
    a[q_][ks_] = *(const bf16x8*)&L[(ab) + (wm * 64 + q_ * 16 + rA) * 64 +       \
                                    ((ks_ * 32 + kk0) ^ xorv)];                  \
    b[q_][ks_] = *(const bf16x8*)&L[(bb) + (wn * 64 + q_ * 16 + rA) * 64 +       \
                                    ((ks_ * 32 + kk0) ^ xorv)];                  \
  }
#define MM(av, bv, cv)                                                           \
  (DT ? __builtin_amdgcn_mfma_f32_16x16x32_f16(                                  \
            __builtin_bit_cast(f16x8, av), __builtin_bit_cast(f16x8, bv), cv,    \
            0, 0, 0)                                                             \
      : __builtin_amdgcn_mfma_f32_16x16x32_bf16(av, bv, cv, 0, 0, 0))
#define MFMA_ALL()                                                               \
  do {                                                                           \
    SETP(1);                                                                     \
    _Pragma("unroll") for (int ks = 0; ks < 2; ++ks)                             \
    _Pragma("unroll") for (int q = 0; q < 4; ++q)                                \
    _Pragma("unroll") for (int p = 0; p < 4; ++p)                                \
        acc[q][p] = MM(a[q][ks], b[p][ks], acc[q][p]);                           \
    SETP(0);                                                                     \
  } while (0)

  f32x4 acc[4][4] = {};
  bf16x8 a[4][2], b[4][2];

  STAGE(0, 0);
  STAGE(1, 1);

  const int NT = K >> 6;  // even for all dispatches
  for (int tt = 0; tt < NT; tt += 2) {
    VMC(8);      // own stage(tt) landed (8 newer = own stage(tt+1))
    BARRIER();
    READ_ALL(0 * 16384, 0 * 16384 + 8192);
    MFMA_ALL();
    BARRIER();
    if (tt + 2 < NT) STAGE(0, tt + 2);
    if (tt + 2 < NT) VMC(8); else VMC(0);  // tail: no newer stages -> full drain
    BARRIER();
    READ_ALL(1 * 16384, 1 * 16384 + 8192);
    MFMA_ALL();
    BARRIER();
    if (tt + 3 < NT) STAGE(1, tt + 3);
  }

  // epilogue: C/D layout col=lane&15, row=(lane>>4)*4+j
  const int row0 = m0 + wm * 64;
  const int col0 = n0 + wn * 64;
  const int cl = lane & 15;
  const int rg = (lane >> 4) * 4;
#pragma unroll
  for (int mi = 0; mi < 4; mi++) {
#pragma unroll
    for (int ni = 0; ni < 4; ni++) {
#pragma unroll
      for (int j = 0; j < 4; j++) {
        const long gm = row0 + mi * 16 + rg + j;
        const int gn = col0 + ni * 16 + cl;
        float val = acc[mi][ni][j];
        if constexpr (EPI == EPI_QKV) {
          if (z < 2) {
            ((bf16*)Cb)[z * cstr + gm * ldc + gn] = (bf16)val;   // q,k bf16
          } else {
            ((f16*)resid)[gm * (long)ldc + gn] = (f16)val;       // v rows fp16
          }
        } else if constexpr (EPI == EPI_F16) {
          ((f16*)Cb)[z * cstr + gm * ldc + gn] = (f16)val;
        } else if constexpr (EPI == EPI_AOS) {
          ((u8*)Cb)[z * cstr + gm * ldc + gn] = to_fp8(val * 0.03125f);  // ao fp8
        }
      }
    }
  }
#undef STAGE
#undef READ_ALL
#undef MM
#undef MFMA_ALL
}

// ========== fp8 128x128xK GEMM: BK=64B, dbuf 32KiB LDS, 4 waves, 2 blocks/CU ========
// C = A[M][K] * B[N][K]^T, A/B fp8 e4m3, mfma_f32_16x16x32_fp8_fp8 (A/B frag = 8B).
// LDS: [buf2][A 128x64B | B 128x64B]. Swizzle (16B-block granular, matches gload16):
//   physical block pb = lb ^ ((row>>1)&3). Derivation: bank(row,blk) = (row*16+4*blk)%32;
//   16-lane read groups have 8 even+8 odd rows; XOR by (row>>1)&3 spreads even rows
//   0,2,4,6 across all 4 blocks (rows r,r+8 collide -> 2-way = free, m136).
// Stage: chunk = 16 rows = 1KB; wave w stages chunks 2w,2w+1 per op; lane l -> row
// 16c+(l>>2), physical block l&3, pre-swizzled SOURCE col 16*((l&3)^((l>>3)&3))
// (rule 21: linear dest + inverse-swizzled source + swizzled read).
// Frag read: row=(sub)*16+rA, k-byte kb = ks*32 + (lane>>4)*8 ->
//   phys = row*64 + ((kb>>4)^((row>>1)&3))*16 + (kb&8); ds_read b64.
// Loop = R15 counted-vmcnt 2-deep (4 loads/wave/tile -> VMC(4); tail VMC(0)).
template <int EPI>
__global__ __launch_bounds__(256, 2) void gemmq_k(
    const u8* __restrict__ Ab, const u8* __restrict__ Bbp, void* __restrict__ Cb,
    const float* __restrict__ bias, const float* __restrict__ resid,
    int K, int lda, int ldb, int ldc) {
  extern __shared__ u8 Lq[];  // 2*2*8192 B = 32 KiB
  const int t = threadIdx.x;
  const int lane = t & 63;
  const int w = t >> 6;
  const int wm = w >> 1, wn = w & 1;

  // XCD-chunked band raster (identical to gemmdb_k)
  const int gx = gridDim.x;
  const int nwg = gx * gridDim.y;
  const int dd = blockIdx.y * gx + blockIdx.x;
  const int cpx = nwg >> 3;
  const int xcd = dd & 7;
  const int idx = dd >> 3;
  const int R = cpx / gx;
  const int H = (R >= 8) ? 8 : R;
  const int bandsz = H * gx;
  const int bnd = idx / bandsz;
  const int rr = idx % bandsz;
  const int m_t = xcd * R + bnd * H + (rr % H);
  const int n_t = rr / H;
  const int m0 = m_t * 128;
  const int n0 = n_t * 128;

  const u8* A;
  if constexpr (EPI == EPI_RESID) {
    const long qo[4] = {0, 67108864, 100663296, 134217728};  // h quarter byte offsets
    A = Ab + qo[m0 >> 12] - (long)(m0 & ~4095) * lda;
  } else {
    A = Ab;
  }
  const u8* Bp = Bbp;

  // staging: chunk = 16 rows x 64B = 1KB; 8 chunks/op; wave w stages chunks 2w,2w+1
  const int lrow = lane >> 2;                            // row within chunk
  const int sc = 16 * ((lane & 3) ^ ((lane >> 3) & 3));  // pre-swizzled byte col
  const u8* gA[2];
  const u8* gB[2];
#pragma unroll
  for (int j = 0; j < 2; ++j) {
    const int r = (w * 2 + j) * 16 + lrow;
    gA[j] = A + (long)(m0 + r) * lda + sc;
    gB[j] = Bp + (long)(n0 + r) * ldb + sc;
  }

#define QSTAGE(buf, tau)                                                         \
  do {                                                                           \
    _Pragma("unroll") for (int j_ = 0; j_ < 2; ++j_)                             \
        gload16(gA[j_] + (long)(tau) * 64,                                       \
                &Lq[(buf)*16384 + (w * 2 + j_) * 1024]);                         \
    _Pragma("unroll") for (int j_ = 0; j_ < 2; ++j_)                             \
        gload16(gB[j_] + (long)(tau) * 64,                                       \
                &Lq[(buf)*16384 + 8192 + (w * 2 + j_) * 1024]);                  \
  } while (0)

  const int rA = lane & 15;
  const int kq = lane >> 4;  // 0..3

#define QREAD_ALL(base)                                                          \
  _Pragma("unroll") for (int q_ = 0; q_ < 4; ++q_)                               \
  _Pragma("unroll") for (int ks_ = 0; ks_ < 2; ++ks_) {                          \
    const int ra_ = wm * 64 + q_ * 16 + rA;                                      \
    const int rb_ = wn * 64 + q_ * 16 + rA;                                      \
    const int kb_ = ks_ * 32 + kq * 8;                                           \
    a[q_][ks_] = *(const u64*)&Lq[(base) + ra_ * 64 +                            \
                                  (((kb_ >> 4) ^ ((ra_ >> 1) & 3)) << 4) +       \
                                  (kb_ & 8)];                                    \
    b[q_][ks_] = *(const u64*)&Lq[(base) + 8192 + rb_ * 64 +                     \
                                  (((kb_ >> 4) ^ ((rb_ >> 1) & 3)) << 4) +       \
                                  (kb_ & 8)];                                    \
  }
#define QMFMA_ALL()                                                              \
  do {                                                                           \
    SETP(1);                                                                     \
    _Pragma("unroll") for (int ks = 0; ks < 2; ++ks)                             \
    _Pragma("unroll") for (int q = 0; q < 4; ++q)                                \
    _Pragma("unroll") for (int p = 0; p < 4; ++p)                                \
        acc[q][p] = __builtin_amdgcn_mfma_f32_16x16x32_fp8_fp8(                  \
            (long)a[q][ks], (long)b[p][ks], acc[q][p], 0, 0, 0);                 \
    SETP(0);                                                                     \
  } while (0)

  f32x4 acc[4][4] = {};
  u64 a[4][2], b[4][2];

  QSTAGE(0, 0);
  QSTAGE(1, 1);

  const int NT = K >> 6;  // even (16 / 64)
  for (int tt = 0; tt < NT; tt += 2) {
    VMC(4);      // own stage(tt) landed (4 newer = own stage(tt+1))
    BARRIER();
    QREAD_ALL(0);
    QMFMA_ALL();
    BARRIER();
    if (tt + 2 < NT) QSTAGE(0, tt + 2);
    if (tt + 2 < NT) VMC(4); else VMC(0);  // tail: full drain
    BARRIER();
    QREAD_ALL(16384);
    QMFMA_ALL();
    BARRIER();
    if (tt + 3 < NT) QSTAGE(1, tt + 3);
  }

  // epilogue: C/D layout col=lane&15, row=(lane>>4)*4+j (dtype-independent)
  const int row0 = m0 + wm * 64;
  const int col0 = n0 + wn * 64;
  const int cl = lane & 15;
  const int rg = (lane >> 4) * 4;
#pragma unroll
  for (int mi = 0; mi < 4; mi++) {
#pragma unroll
    for (int ni = 0; ni < 4; ni++) {
#pragma unroll
      for (int j = 0; j < 4; j++) {
        const long gm = row0 + mi * 16 + rg + j;
        const int gn = col0 + ni * 16 + cl;
        float val = acc[mi][ni][j];
        if constexpr (EPI == EPI_SWISH) {
          const long qoc[4] = {0, 67108864, 100663296, 134217728};  // byte offs
          u8* hq = (u8*)Cb + qoc[m0 >> 12];
          float hv = val + bias[gn];
          hq[(long)(gm & 4095) * ldc + gn] = to_fp8(hv / (1.0f + __expf(-hv)));
        } else {  // EPI_RESID
          ((float*)Cb)[gm * (long)ldc + gn] = val + bias[gn] + resid[gm * (long)ldc + gn];
        }
      }
    }
  }
#undef QSTAGE
#undef QREAD_ALL
#undef QMFMA_ALL
}

extern "C" void kernel_launch(void* const* d_in, const int* in_sizes, int n_in,
                              void* d_out, int out_size, void* d_ws, size_t ws_size,
                              hipStream_t stream) {
  const float* x  = (const float*)d_in[0];
  const float* g  = (const float*)d_in[1];
  const float* be = (const float*)d_in[2];
  const float* Wq = (const float*)d_in[3];
  const float* Wk = (const float*)d_in[4];
  const float* Wv = (const float*)d_in[5];
  const float* W1 = (const float*)d_in[6];
  const float* b1 = (const float*)d_in[7];
  const float* W2 = (const float*)d_in[8];
  const float* b2 = (const float*)d_in[9];

  hipFuncSetAttribute((const void*)&gemmdb_k<EPI_QKV, 0>,
                      hipFuncAttributeMaxDynamicSharedMemorySize, 65536);
  hipFuncSetAttribute((const void*)&gemmdb_k<EPI_F16, 0>,
                      hipFuncAttributeMaxDynamicSharedMemorySize, 65536);
  hipFuncSetAttribute((const void*)&gemmdb_k<EPI_AOS, 1>,
                      hipFuncAttributeMaxDynamicSharedMemorySize, 65536);
  hipFuncSetAttribute((const void*)&gemmq_k<EPI_SWISH>,
                      hipFuncAttributeMaxDynamicSharedMemorySize, 32768);
  hipFuncSetAttribute((const void*)&gemmq_k<EPI_RESID>,
                      hipFuncAttributeMaxDynamicSharedMemorySize, 32768);

  // ---- workspace overlay (bytes) ----
  // [0,33.5M): xn -> scores_lo -> h q0 (fp8, 16.8M)
  // [33.5,67.1M): q -> ao (fp8, 16.8M)
  // [67.1,100.6M): k -> h q1     [100.6,134.2M): vT -> h q2
  // [134.2,167.8M): vrows -> scores_hi -> h q3
  // [167.8M..): wqkvT bf16, w1T8 fp8, w2T8 fp8
  char* ws = (char*)d_ws;
  bf16* xn        = (bf16*)(ws + 0);
  f16*  scores_lo = (f16*)(ws + 0);
  bf16* q         = (bf16*)(ws + 33554432);
  u8*   ao        = (u8*)(ws + 33554432);      // fp8, after q dies
  bf16* kk        = (bf16*)(ws + 67108864);
  f16*  vT        = (f16*)(ws + 100663296);
  f16*  vrows     = (f16*)(ws + 134217728);
  f16*  scores_hi = (f16*)(ws + 134217728);
  bf16* wqT       = (bf16*)(ws + 167772160);
  u8*   w1T8      = (u8*)(ws + 174063616);     // [4096][1024] fp8
  u8*   w2T8      = (u8*)(ws + 182452224);     // [1024][4096] fp8

  tcast_k<<<dim3(32, 32), 256, 0, stream>>>(Wq, wqT, 1024, 1024);
  tcast_k<<<dim3(32, 32), 256, 0, stream>>>(Wk, wqT + 1048576, 1024, 1024);
  tcast_k<<<dim3(32, 32), 256, 0, stream>>>(Wv, wqT + 2097152, 1024, 1024);
  tcast8_k<<<dim3(128, 32), 256, 0, stream>>>(W1, w1T8, 1024, 4096);
  tcast8_k<<<dim3(32, 128), 256, 0, stream>>>(W2, w2T8, 4096, 1024);

  ln_k<<<16384, 256, 0, stream>>>(x, g, be, xn);

  // QKV: z=0,1 -> q,k bf16; z=2 -> v rows fp16 via resid ptr
  gemmdb_k<EPI_QKV, 0><<<dim3(8, 128, 3), 256, 65536, stream>>>(
      xn, wqT, q, nullptr, (const float*)vrows, 1024, 1024, 1024, 1024,
      0L, 1048576L, 16777216L);

  tbf16_k<<<dim3(16, 32, 8), 256, 0, stream>>>(vrows, vT);

  // scores: two fp16 slabs
  gemmdb_k<EPI_F16, 0><<<dim3(16, 16, 4), 256, 65536, stream>>>(
      q, kk, scores_lo, nullptr, nullptr,
      1024, 1024, 1024, 2048, 2097152L, 2097152L, 4194304L);
  gemmdb_k<EPI_F16, 0><<<dim3(16, 16, 4), 256, 65536, stream>>>(
      q + 4L * 2097152, kk + 4L * 2097152, scores_hi, nullptr, nullptr,
      1024, 1024, 1024, 2048, 2097152L, 2097152L, 4194304L);

  softmax16_k<<<16384, 256, 0, stream>>>(scores_lo, scores_hi);

  // PV: single launch, all 8 batches; epilogue writes ao as fp8 (*1/32)
  gemmdb_k<EPI_AOS, 1><<<dim3(8, 16, 8), 256, 65536, stream>>>(
      (const bf16*)scores_lo, (const bf16*)vT, ao, (const float*)scores_hi, nullptr,
      2048, 2048, 2048, 1024, 4194304L, 2097152L, 2097152L);

  // MLP1 (fp8): h (quartered fp8) = swish(ao @ W1 + b1)
  gemmq_k<EPI_SWISH><<<dim3(32, 128, 1), 256, 32768, stream>>>(
      ao, w1T8, ws, b1, nullptr, 1024, 1024, 1024, 4096);
  // MLP2 (fp8): out = h @ W2 + b2 + x
  gemmq_k<EPI_RESID><<<dim3(8, 128, 1), 256, 32768, stream>>>(
      (const u8*)ws, w2T8, d_out, b2, x, 4096, 4096, 4096, 1024);
}

// Round 17
// 467.440 us; speedup vs baseline: 1.5068x; 1.1632x over previous
//
#include <hip/hip_runtime.h>
#include <hip/hip_fp8.h>

// EncoderBlock: B=8, S=2048, D=1024, H=4096, single-head attn (scale AFTER softmax),
// LN -> QKV -> scores -> softmax*(1/32) -> PV -> MLP(Swish) -> +residual.
// Round 17: FULL fp8 compute path. All five GEMMs run the R16 gemmq core (fp8 e4m3,
// 32KiB dbuf, counted-vmcnt 2-deep, band raster). Probs stored fp8 x256 (avoids e4m3
// subnormal flush; 1/(32*256) folded into PV epilogue). Softmax near-one-hot (score
// sigma~13, top-gap~5) => fp8 score noise (sigma~1) rarely flips argmax -> accuracy safe.
// WS = 190,840,832 B. Overlay (bytes):
//  [0,16.8M): xn8 -> | [0,33.5M): scores_lo f16 -> h q0 at 0
//  [33.5,50.3M): q8 -> ao8   [50.3,67.1M): k8
//  [67.1,100.6M): vrows f16 -> h q1 at 67.1M
//  [100.6,134.2M): scores_hi f16 -> h q2 at 100.6M
//  [134.2,151M): vT8 -> h q3 at 134.2M
//  [167.8M..): wq8/wk8/wv8 (3x1M), w1T8 (4.2M), w2T8 (4.2M)

#define Bb_ 8
#define Ss_ 2048
#define Dd_ 1024
#define Hh_ 4096

typedef __bf16 bf16;
typedef _Float16 f16;
typedef unsigned char u8;
typedef unsigned int u32;
typedef unsigned long long u64;
typedef __attribute__((ext_vector_type(8))) _Float16 f16x8;
typedef __attribute__((ext_vector_type(4))) float f32x4;

enum { EPI_QKV = 0, EPI_SCORE = 1, EPI_AOS = 2, EPI_SWISH = 3, EPI_RESID = 4 };

__device__ __forceinline__ void gload16(const void* g, void* l) {
  __builtin_amdgcn_global_load_lds(
      (const __attribute__((address_space(1))) void*)g,
      (__attribute__((address_space(3))) void*)l, 16, 0, 0);
}

__device__ __forceinline__ u8 to_fp8(float f) {
  __hip_fp8_e4m3 v(f);  // OCP e4m3fn (gfx950 native)
  return (u8)v.__x;
}

#define SETP(x) __builtin_amdgcn_s_setprio(x)
#define BARRIER()                          \
  do {                                     \
    asm volatile("" ::: "memory");         \
    __builtin_amdgcn_s_barrier();          \
    asm volatile("" ::: "memory");         \
  } while (0)
#define VMC(n) asm volatile("s_waitcnt vmcnt(" #n ")" ::: "memory")

// ---------- transpose-cast: W[K][N] f32 -> WT[N][K] fp8 e4m3 ----------
__global__ __launch_bounds__(256) void tcast8_k(const float* __restrict__ W,
                                                u8* __restrict__ WT, int K, int N) {
  __shared__ float tile[32][33];
  const int tn0 = blockIdx.x * 32;
  const int tk0 = blockIdx.y * 32;
  const int t = threadIdx.x;
  const int c = t & 31;
  const int r4 = t >> 5;
#pragma unroll
  for (int i = 0; i < 4; i++) {
    int r = r4 + i * 8;
    tile[r][c] = W[(long)(tk0 + r) * N + (tn0 + c)];
  }
  __syncthreads();
#pragma unroll
  for (int i = 0; i < 4; i++) {
    int r = r4 + i * 8;
    WT[(long)(tn0 + r) * K + (tk0 + c)] = to_fp8(tile[c][r]);
  }
}

// ---------- v transpose+cast: vrows f16 [z][2048][1024] -> vT8 u8 [z][1024][2048] ----
__global__ __launch_bounds__(256) void tv8_k(const f16* __restrict__ V,
                                             u8* __restrict__ VT) {
  __shared__ f16 tile[64][72];
  const long z = blockIdx.z;
  const int n0 = blockIdx.x * 64;
  const int k0 = blockIdx.y * 64;
  const int t = threadIdx.x;
  const int r = t >> 3;
  const int c = (t & 7) * 8;
  const f16* Vb = V + z * (long)(Ss_ * Dd_);
  u8* VTb = VT + z * (long)(Dd_ * Ss_);
#pragma unroll
  for (int i = 0; i < 2; i++)
    *(f16x8*)&tile[r + i * 32][c] =
        *(const f16x8*)(Vb + (long)(k0 + r + i * 32) * Dd_ + n0 + c);
  __syncthreads();
#pragma unroll
  for (int i = 0; i < 2; i++) {
    const int n = r + i * 32;
    union { u8 b[8]; u64 w; } ov;
#pragma unroll
    for (int j = 0; j < 8; j++) ov.b[j] = to_fp8((float)tile[c + j][n]);
    *(u64*)(VTb + (long)(n0 + n) * Ss_ + k0 + c) = ov.w;
  }
}

// ---------- LayerNorm: x[row][1024] f32 -> xn fp8 ----------
__global__ __launch_bounds__(256) void ln8_k(const float* __restrict__ x,
                                             const float* __restrict__ gamma,
                                             const float* __restrict__ beta,
                                             u8* __restrict__ xn) {
  const long row = blockIdx.x;
  const float* xr = x + row * Dd_;
  const int t = threadIdx.x;
  float4 v = *(const float4*)(xr + t * 4);
  float s = v.x + v.y + v.z + v.w;
  float sq = v.x * v.x + v.y * v.y + v.z * v.z + v.w * v.w;
#pragma unroll
  for (int o = 32; o > 0; o >>= 1) {
    s += __shfl_down(s, o);
    sq += __shfl_down(sq, o);
  }
  __shared__ float ls[4], lq[4];
  const int wid = t >> 6;
  if ((t & 63) == 0) { ls[wid] = s; lq[wid] = sq; }
  __syncthreads();
  if (t == 0) {
    float S = ls[0] + ls[1] + ls[2] + ls[3];
    float Q = lq[0] + lq[1] + lq[2] + lq[3];
    float mu = S * (1.0f / Dd_);
    float var = Q * (1.0f / Dd_) - mu * mu;
    ls[0] = mu;
    lq[0] = rsqrtf(var + 1e-5f);
  }
  __syncthreads();
  const float mu = ls[0], rstd = lq[0];
  float4 g = *(const float4*)(gamma + t * 4);
  float4 be = *(const float4*)(beta + t * 4);
  u32 pk = (u32)to_fp8((v.x - mu) * rstd * g.x + be.x) |
           ((u32)to_fp8((v.y - mu) * rstd * g.y + be.y) << 8) |
           ((u32)to_fp8((v.z - mu) * rstd * g.z + be.z) << 16) |
           ((u32)to_fp8((v.w - mu) * rstd * g.w + be.w) << 24);
  *(u32*)(xn + row * (long)Dd_ + t * 4) = pk;
}

// ---------- softmax: f16 scores (two slabs) -> fp8 probs x256, in place ----------
// Probs scaled by 256 (max prob ~1 -> 256 <= e4m3 max 448; avoids subnormal flush);
// 1/(32*256) applied in PV epilogue. In-place safe: all row reads precede the first
// barrier; fp8 writes (first quarter of row bytes) happen after the last barrier.
__global__ __launch_bounds__(256) void softmax8_k(f16* __restrict__ lo,
                                                  f16* __restrict__ hi) {
  const long row = blockIdx.x;
  const long z = row >> 11;
  f16* sr = (z < 4 ? lo + z * 4194304L : hi + (z - 4) * 4194304L) +
            (row & 2047) * (long)Ss_;
  const int t = threadIdx.x;
  f16x8 v = *(const f16x8*)(sr + t * 8);
  float f[8];
#pragma unroll
  for (int j = 0; j < 8; j++) f[j] = (float)v[j];
  float vm = f[0];
#pragma unroll
  for (int j = 1; j < 8; j++) vm = fmaxf(vm, f[j]);
  __shared__ float red[4];
#pragma unroll
  for (int o = 32; o > 0; o >>= 1) vm = fmaxf(vm, __shfl_xor(vm, o));
  const int wid = t >> 6;
  if ((t & 63) == 0) red[wid] = vm;
  __syncthreads();
  vm = fmaxf(fmaxf(red[0], red[1]), fmaxf(red[2], red[3]));
  float e[8], s = 0.f;
#pragma unroll
  for (int j = 0; j < 8; j++) { e[j] = __expf(f[j] - vm); s += e[j]; }
#pragma unroll
  for (int o = 32; o > 0; o >>= 1) s += __shfl_xor(s, o);
  __syncthreads();
  if ((t & 63) == 0) red[wid] = s;
  __syncthreads();
  s = red[0] + red[1] + red[2] + red[3];
  const float rs = 256.0f / s;
  union { u8 b[8]; u64 w; } ov;
#pragma unroll
  for (int j = 0; j < 8; j++) ov.b[j] = to_fp8(e[j] * rs);
  *(u64*)((u8*)sr + t * 8) = ov.w;
}

// ========== fp8 128x128xK GEMM: BK=64B, dbuf 32KiB LDS, 4 waves, 2 blocks/CU ========
// C = A[M][K] * B[N][K]^T, A/B fp8 e4m3, mfma_f32_16x16x32_fp8_fp8 (A/B frag = 8B).
// LDS: [buf2][A 128x64B | B 128x64B]. Swizzle: 16B-block pb = lb ^ ((row>>1)&3)
// (rows r,r+8 2-way = acceptable); staged via pre-swizzled GLOBAL source col
// 16*((l&3)^((l>>3)&3)) + linear gload_lds dest (rule 21 both-sides).
// Loop: R15 counted-vmcnt 2-deep (4 loads/wave/tile -> VMC(4); tail VMC(0)).
// XCD-chunked L2 band raster (R12). lda/ldb in BYTES.
template <int EPI>
__global__ __launch_bounds__(256, 2) void gemmq_k(
    const u8* __restrict__ Ab, const u8* __restrict__ Bbp, void* __restrict__ Cb,
    const float* __restrict__ bias, const float* __restrict__ resid,
    int K, int lda, int ldb, int ldc, long astr, long bstr, long cstr) {
  extern __shared__ u8 Lq[];  // 2*2*8192 B = 32 KiB
  const int t = threadIdx.x;
  const int lane = t & 63;
  const int w = t >> 6;
  const int wm = w >> 1, wn = w & 1;

  // XCD-chunked band raster (bijective; all grids: nwg%8==0, gx|cpx, H|R)
  const int gx = gridDim.x;
  const int nwg = gx * gridDim.y;
  const int dd = blockIdx.y * gx + blockIdx.x;
  const int cpx = nwg >> 3;
  const int xcd = dd & 7;
  const int idx = dd >> 3;
  const int R = cpx / gx;
  const int H = (R >= 8) ? 8 : R;
  const int bandsz = H * gx;
  const int bnd = idx / bandsz;
  const int rr = idx % bandsz;
  const int m_t = xcd * R + bnd * H + (rr % H);
  const int n_t = rr / H;
  const int m0 = m_t * 128;
  const int n0 = n_t * 128;

  const long z = blockIdx.z;
  const u8* A;
  if constexpr (EPI == EPI_RESID) {
    const long qo[4] = {0, 67108864, 100663296, 134217728};  // h quarter byte offsets
    A = Ab + qo[m0 >> 12] - (long)(m0 & ~4095) * lda;
  } else if constexpr (EPI == EPI_AOS) {
    A = (z < 4) ? Ab + z * astr : (const u8*)bias + (z - 4) * astr;  // probs slabs
  } else if constexpr (EPI == EPI_SWISH) {
    A = Ab;
  } else {  // EPI_QKV (astr=0), EPI_SCORE (per-batch)
    A = Ab + z * astr;
  }
  const u8* Bp = Bbp + z * bstr;

  // staging: chunk = 16 rows x 64B = 1KB; 8 chunks/op; wave w stages chunks 2w,2w+1
  const int lrow = lane >> 2;                            // row within chunk
  const int sc = 16 * ((lane & 3) ^ ((lane >> 3) & 3));  // pre-swizzled byte col
  const u8* gA[2];
  const u8* gB[2];
#pragma unroll
  for (int j = 0; j < 2; ++j) {
    const int r = (w * 2 + j) * 16 + lrow;
    gA[j] = A + (long)(m0 + r) * lda + sc;
    gB[j] = Bp + (long)(n0 + r) * ldb + sc;
  }

#define QSTAGE(buf, tau)                                                         \
  do {                                                                           \
    _Pragma("unroll") for (int j_ = 0; j_ < 2; ++j_)                             \
        gload16(gA[j_] + (long)(tau) * 64,                                       \
                &Lq[(buf)*16384 + (w * 2 + j_) * 1024]);                         \
    _Pragma("unroll") for (int j_ = 0; j_ < 2; ++j_)                             \
        gload16(gB[j_] + (long)(tau) * 64,                                       \
                &Lq[(buf)*16384 + 8192 + (w * 2 + j_) * 1024]);                  \
  } while (0)

  const int rA = lane & 15;
  const int kq = lane >> 4;  // 0..3

#define QREAD_ALL(base)                                                          \
  _Pragma("unroll") for (int q_ = 0; q_ < 4; ++q_)                               \
  _Pragma("unroll") for (int ks_ = 0; ks_ < 2; ++ks_) {                          \
    const int ra_ = wm * 64 + q_ * 16 + rA;                                      \
    const int rb_ = wn * 64 + q_ * 16 + rA;                                      \
    const int kb_ = ks_ * 32 + kq * 8;                                           \
    a[q_][ks_] = *(const u64*)&Lq[(base) + ra_ * 64 +                            \
                                  (((kb_ >> 4) ^ ((ra_ >> 1) & 3)) << 4) +       \
                                  (kb_ & 8)];                                    \
    b[q_][ks_] = *(const u64*)&Lq[(base) + 8192 + rb_ * 64 +                     \
                                  (((kb_ >> 4) ^ ((rb_ >> 1) & 3)) << 4) +       \
                                  (kb_ & 8)];                                    \
  }
#define QMFMA_ALL()                                                              \
  do {                                                                           \
    SETP(1);                                                                     \
    _Pragma("unroll") for (int ks = 0; ks < 2; ++ks)                             \
    _Pragma("unroll") for (int q = 0; q < 4; ++q)                                \
    _Pragma("unroll") for (int p = 0; p < 4; ++p)                                \
        acc[q][p] = __builtin_amdgcn_mfma_f32_16x16x32_fp8_fp8(                  \
            (long)a[q][ks], (long)b[p][ks], acc[q][p], 0, 0, 0);                 \
    SETP(0);                                                                     \
  } while (0)

  f32x4 acc[4][4] = {};
  u64 a[4][2], b[4][2];

  QSTAGE(0, 0);
  QSTAGE(1, 1);

  const int NT = K >> 6;  // even for all dispatches (16/16/32/16/64)
  for (int tt = 0; tt < NT; tt += 2) {
    VMC(4);      // own stage(tt) landed (4 newer = own stage(tt+1))
    BARRIER();
    QREAD_ALL(0);
    QMFMA_ALL();
    BARRIER();
    if (tt + 2 < NT) QSTAGE(0, tt + 2);
    if (tt + 2 < NT) VMC(4); else VMC(0);  // tail: full drain
    BARRIER();
    QREAD_ALL(16384);
    QMFMA_ALL();
    BARRIER();
    if (tt + 3 < NT) QSTAGE(1, tt + 3);
  }

  // epilogue: C/D layout col=lane&15, row=(lane>>4)*4+j (dtype-independent)
  const int row0 = m0 + wm * 64;
  const int col0 = n0 + wn * 64;
  const int cl = lane & 15;
  const int rg = (lane >> 4) * 4;
#pragma unroll
  for (int mi = 0; mi < 4; mi++) {
#pragma unroll
    for (int ni = 0; ni < 4; ni++) {
#pragma unroll
      for (int j = 0; j < 4; j++) {
        const long gm = row0 + mi * 16 + rg + j;
        const int gn = col0 + ni * 16 + cl;
        float val = acc[mi][ni][j];
        if constexpr (EPI == EPI_QKV) {
          if (z < 2) {
            ((u8*)Cb)[z * cstr + gm * ldc + gn] = to_fp8(val);     // q,k fp8
          } else {
            ((f16*)resid)[gm * (long)ldc + gn] = (f16)val;         // v rows f16
          }
        } else if constexpr (EPI == EPI_SCORE) {
          f16* dst = (z < 4) ? (f16*)Cb : (f16*)bias;              // lo/hi slab
          dst[(z & 3) * cstr + gm * ldc + gn] = (f16)val;
        } else if constexpr (EPI == EPI_AOS) {
          // probs were stored x256; post-softmax scale 1/32 -> val/8192
          ((u8*)Cb)[z * cstr + gm * ldc + gn] = to_fp8(val * (1.0f / 8192.0f));
        } else if constexpr (EPI == EPI_SWISH) {
          const long qoc[4] = {0, 67108864, 100663296, 134217728};  // byte offs
          u8* hq = (u8*)Cb + qoc[m0 >> 12];
          float hv = val + bias[gn];
          hq[(long)(gm & 4095) * ldc + gn] = to_fp8(hv / (1.0f + __expf(-hv)));
        } else {  // EPI_RESID
          ((float*)Cb)[gm * (long)ldc + gn] = val + bias[gn] + resid[gm * (long)ldc + gn];
        }
      }
    }
  }
#undef QSTAGE
#undef QREAD_ALL
#undef QMFMA_ALL
}

extern "C" void kernel_launch(void* const* d_in, const int* in_sizes, int n_in,
                              void* d_out, int out_size, void* d_ws, size_t ws_size,
                              hipStream_t stream) {
  const float* x  = (const float*)d_in[0];
  const float* g  = (const float*)d_in[1];
  const float* be = (const float*)d_in[2];
  const float* Wq = (const float*)d_in[3];
  const float* Wk = (const float*)d_in[4];
  const float* Wv = (const float*)d_in[5];
  const float* W1 = (const float*)d_in[6];
  const float* b1 = (const float*)d_in[7];
  const float* W2 = (const float*)d_in[8];
  const float* b2 = (const float*)d_in[9];

  hipFuncSetAttribute((const void*)&gemmq_k<EPI_QKV>,
                      hipFuncAttributeMaxDynamicSharedMemorySize, 32768);
  hipFuncSetAttribute((const void*)&gemmq_k<EPI_SCORE>,
                      hipFuncAttributeMaxDynamicSharedMemorySize, 32768);
  hipFuncSetAttribute((const void*)&gemmq_k<EPI_AOS>,
                      hipFuncAttributeMaxDynamicSharedMemorySize, 32768);
  hipFuncSetAttribute((const void*)&gemmq_k<EPI_SWISH>,
                      hipFuncAttributeMaxDynamicSharedMemorySize, 32768);
  hipFuncSetAttribute((const void*)&gemmq_k<EPI_RESID>,
                      hipFuncAttributeMaxDynamicSharedMemorySize, 32768);

  // ---- workspace overlay (bytes); see header comment ----
  char* ws = (char*)d_ws;
  u8*   xn8       = (u8*)(ws + 0);
  f16*  scores_lo = (f16*)(ws + 0);            // after xn8 dies (post-QKV)
  u8*   q8        = (u8*)(ws + 33554432);
  u8*   ao8       = (u8*)(ws + 33554432);      // after q8 dies (post-scores)
  u8*   k8        = (u8*)(ws + 50331648);
  f16*  vrows     = (f16*)(ws + 67108864);     // f16 [16384][1024]
  f16*  scores_hi = (f16*)(ws + 100663296);
  u8*   vT8       = (u8*)(ws + 134217728);     // [8][1024][2048]
  u8*   wq8       = (u8*)(ws + 167772160);     // wq/wk/wv fp8, stride 1048576
  u8*   w1T8      = (u8*)(ws + 170917888);     // [4096][1024] fp8
  u8*   w2T8      = (u8*)(ws + 175112192);     // [1024][4096] fp8
  // h quarters (fp8) at {0, 67108864, 100663296, 134217728} (EPI_SWISH/RESID).

  tcast8_k<<<dim3(32, 32), 256, 0, stream>>>(Wq, wq8, 1024, 1024);
  tcast8_k<<<dim3(32, 32), 256, 0, stream>>>(Wk, wq8 + 1048576, 1024, 1024);
  tcast8_k<<<dim3(32, 32), 256, 0, stream>>>(Wv, wq8 + 2097152, 1024, 1024);
  tcast8_k<<<dim3(128, 32), 256, 0, stream>>>(W1, w1T8, 1024, 4096);
  tcast8_k<<<dim3(32, 128), 256, 0, stream>>>(W2, w2T8, 4096, 1024);

  ln8_k<<<16384, 256, 0, stream>>>(x, g, be, xn8);

  // QKV (fp8): z=0,1 -> q8,k8 fp8; z=2 -> vrows f16 via resid ptr
  gemmq_k<EPI_QKV><<<dim3(8, 128, 3), 256, 32768, stream>>>(
      xn8, wq8, q8, nullptr, (const float*)vrows,
      1024, 1024, 1024, 1024, 0L, 1048576L, 16777216L);

  tv8_k<<<dim3(16, 32, 8), 256, 0, stream>>>(vrows, vT8);

  // scores (fp8 x fp8 -> f16), all 8 batches; hi slab via bias ptr
  gemmq_k<EPI_SCORE><<<dim3(16, 16, 8), 256, 32768, stream>>>(
      q8, k8, scores_lo, (const float*)scores_hi, nullptr,
      1024, 1024, 1024, 2048, 2097152L, 2097152L, 4194304L);

  softmax8_k<<<16384, 256, 0, stream>>>(scores_lo, scores_hi);

  // PV (fp8 probs x fp8 vT -> ao fp8), all 8 batches; probs_hi via bias ptr
  gemmq_k<EPI_AOS><<<dim3(8, 16, 8), 256, 32768, stream>>>(
      (const u8*)scores_lo, vT8, ao8, (const float*)scores_hi, nullptr,
      2048, 4096, 2048, 1024, 8388608L, 2097152L, 2097152L);

  // MLP1 (fp8): h (quartered fp8) = swish(ao @ W1 + b1)
  gemmq_k<EPI_SWISH><<<dim3(32, 128, 1), 256, 32768, stream>>>(
      ao8, w1T8, ws, b1, nullptr, 1024, 1024, 1024, 4096, 0L, 0L, 0L);
  // MLP2 (fp8): out = h @ W2 + b2 + x
  gemmq_k<EPI_RESID><<<dim3(8, 128, 1), 256, 32768, stream>>>(
      (const u8*)ws, w2T8, d_out, b2, x, 4096, 4096, 4096, 1024, 0L, 0L, 0L);
}